// Round 1
// baseline (12175.341 us; speedup 1.0000x reference)
//
#include <hip/hip_runtime.h>
#include <hip/hip_bf16.h>
#include <math.h>

// Problem constants (shapes are static in the reference)
#define S_   256
#define B_   32
#define H_   512
#define E_   256
#define V_   10000
#define K_   3
#define T_   32
#define N1_  96            // B*K
#define BOS_ 1
#define EOS_ 1
#define NEG_ (-1000000000.0f)

// ---------------------------------------------------------------------------
// Generic fp32 tiled GEMM: C[n][m] = sum_k A[n][k]*Brow(k)[m] (+bias1+bias2)
// Brow(k) = B1 + k*M for k < split, else B2 + (k-split)*M.
// Tile 64x64, TK=16, 256 threads, thread tile 4x4.
// Requires Kd % 16 == 0 (true for 512 and 1280). Handles N, M edge guards.
// ---------------------------------------------------------------------------
__global__ __launch_bounds__(256) void gemm_k(
    const float* __restrict__ A, const float* __restrict__ B1,
    const float* __restrict__ B2, int split,
    const float* __restrict__ bias1, const float* __restrict__ bias2,
    float* __restrict__ C, int N, int Kd, int M)
{
  __shared__ float As[16][64];
  __shared__ float Bs[16][64];
  const int tid = threadIdx.x;
  const int m0 = blockIdx.x * 64;
  const int n0 = blockIdx.y * 64;
  const int tm = tid & 15, tn = tid >> 4;
  const int la_n = tid & 63;            // A loader: one n, 4 consecutive k
  const int la_k = (tid >> 6) * 4;
  const int lb_m = (tid & 15) * 4;      // B loader: one k row, 4 consecutive m
  const int lb_k = tid >> 4;

  float acc[4][4] = {};

  for (int k0 = 0; k0 < Kd; k0 += 16) {
    // stage A tile (transposed to [k][n])
    {
      int n = n0 + la_n;
      float4 av = make_float4(0.f, 0.f, 0.f, 0.f);
      if (n < N) av = *(const float4*)(A + (size_t)n * Kd + k0 + la_k);
      As[la_k + 0][la_n] = av.x; As[la_k + 1][la_n] = av.y;
      As[la_k + 2][la_n] = av.z; As[la_k + 3][la_n] = av.w;
    }
    // stage B tile [k][m]
    {
      int krow = k0 + lb_k;
      const float* Brow = (krow < split) ? (B1 + (size_t)krow * M)
                                         : (B2 + (size_t)(krow - split) * M);
      int m = m0 + lb_m;
      float4 bv;
      if (m + 3 < M) {
        bv = *(const float4*)(Brow + m);
      } else {
        bv.x = (m + 0 < M) ? Brow[m + 0] : 0.f;
        bv.y = (m + 1 < M) ? Brow[m + 1] : 0.f;
        bv.z = (m + 2 < M) ? Brow[m + 2] : 0.f;
        bv.w = (m + 3 < M) ? Brow[m + 3] : 0.f;
      }
      *(float4*)&Bs[lb_k][lb_m] = bv;
    }
    __syncthreads();
#pragma unroll
    for (int kk = 0; kk < 16; kk++) {
      float4 av = *(const float4*)&As[kk][tn * 4];
      float4 bv = *(const float4*)&Bs[kk][tm * 4];
      float a[4] = {av.x, av.y, av.z, av.w};
      float b[4] = {bv.x, bv.y, bv.z, bv.w};
#pragma unroll
      for (int i = 0; i < 4; i++)
#pragma unroll
        for (int j = 0; j < 4; j++) acc[i][j] += a[i] * b[j];
    }
    __syncthreads();
  }

#pragma unroll
  for (int i = 0; i < 4; i++) {
    int n = n0 + tn * 4 + i;
    if (n >= N) continue;
#pragma unroll
    for (int j = 0; j < 4; j++) {
      int m = m0 + tm * 4 + j;
      if (m >= M) continue;
      float v = acc[i][j];
      if (bias1) v += bias1[m];
      if (bias2) v += bias2[m];
      C[(size_t)n * M + m] = v;
    }
  }
}

// ---------------------------------------------------------------------------
// Attention scores: sc[n][s] = dot(tanh(pp[n] + encp[s,b]), Wv), masked.
// grid (8, N); block 256 = 4 waves; wave handles 8 s values.
// ---------------------------------------------------------------------------
__global__ __launch_bounds__(256) void score_k(
    const float* __restrict__ pp, const float* __restrict__ encp,
    const float* __restrict__ Wv, const float* __restrict__ mask,
    float* __restrict__ sc, int bdiv)
{
  const int n = blockIdx.y;
  const int b = n / bdiv;
  const int tid = threadIdx.x;
  const int lane = tid & 63;
  const int w = tid >> 6;
  const float* ppn = pp + (size_t)n * H_;
#pragma unroll
  for (int r = 0; r < 8; r++) {
    int s = blockIdx.x * 32 + w * 8 + r;
    const float* ep = encp + ((size_t)s * B_ + b) * H_;
    float acc = 0.f;
    for (int hh = lane; hh < H_; hh += 64)
      acc += tanhf(ppn[hh] + ep[hh]) * Wv[hh];
#pragma unroll
    for (int off = 32; off; off >>= 1) acc += __shfl_xor(acc, off);
    if (lane == 0)
      sc[(size_t)n * S_ + s] = (mask[(size_t)b * S_ + s] == 0.f) ? NEG_ : acc;
  }
}

// softmax over S=256 per n, in-place in sc. grid N, block 256.
__global__ __launch_bounds__(256) void softmax_k(float* __restrict__ sc)
{
  __shared__ float red[256];
  const int n = blockIdx.x, tid = threadIdx.x;
  float v = sc[(size_t)n * S_ + tid];
  red[tid] = v; __syncthreads();
  for (int s = 128; s; s >>= 1) {
    if (tid < s) red[tid] = fmaxf(red[tid], red[tid + s]);
    __syncthreads();
  }
  float mx = red[0]; __syncthreads();
  float e = expf(v - mx);
  red[tid] = e; __syncthreads();
  for (int s = 128; s; s >>= 1) {
    if (tid < s) red[tid] += red[tid + s];
    __syncthreads();
  }
  sc[(size_t)n * S_ + tid] = e / red[0];
}

// ctx[n][h] = sum_s a[n][s] * enc[s,b,h].  grid (2, N), block 256.
__global__ __launch_bounds__(256) void ctx_k(
    const float* __restrict__ a, const float* __restrict__ enc,
    float* __restrict__ ctx, int bdiv)
{
  const int n = blockIdx.y;
  const int b = n / bdiv;
  const int hh = blockIdx.x * 256 + threadIdx.x;
  float acc = 0.f;
  const float* arow = a + (size_t)n * S_;
  for (int s = 0; s < S_; s++)
    acc += arow[s] * enc[((size_t)s * B_ + b) * H_ + hh];
  ctx[(size_t)n * H_ + hh] = acc;
}

// xcat[n] = [emb[tok[n]] | ctx[n] | h[n]]  (1280). grid N, block 256.
__global__ __launch_bounds__(256) void xcat_k(
    const float* __restrict__ emb, const int* __restrict__ tok,
    const float* __restrict__ ctx, const float* __restrict__ h,
    float* __restrict__ xcat, int tok_is_bos)
{
  const int n = blockIdx.x, tid = threadIdx.x;
  const int tk = tok_is_bos ? BOS_ : tok[n];
  const float* e = emb + (size_t)tk * E_;
  float* xr = xcat + (size_t)n * 1280;
  xr[tid] = e[tid];
  for (int i = tid; i < H_; i += 256) {
    xr[E_ + i] = ctx[(size_t)n * H_ + i];
    xr[E_ + H_ + i] = h[(size_t)n * H_ + i];
  }
}

__device__ __forceinline__ float sigf(float x) { return 1.f / (1.f + expf(-x)); }

// LSTM pointwise + assemble x2 = [ex | h2 | ctx]. grid N, block 256.
__global__ __launch_bounds__(256) void lstm_k(
    const float* __restrict__ gts, const float* __restrict__ cprev,
    const float* __restrict__ ctx, const float* __restrict__ xcat,
    float* __restrict__ h2, float* __restrict__ c2, float* __restrict__ x2)
{
  const int n = blockIdx.x, tid = threadIdx.x;
  const float* g = gts + (size_t)n * (4 * H_);
  float* x2r = x2 + (size_t)n * 1280;
  x2r[tid] = xcat[(size_t)n * 1280 + tid];   // copy ex (256)
  for (int i = tid; i < H_; i += 256) {
    float gi = g[i], gf = g[H_ + i], gg = g[2 * H_ + i], go = g[3 * H_ + i];
    float cc = cprev[(size_t)n * H_ + i];
    float cv = sigf(gf) * cc + sigf(gi) * tanhf(gg);
    float hv = sigf(go) * tanhf(cv);
    c2[(size_t)n * H_ + i] = cv;
    h2[(size_t)n * H_ + i] = hv;
    x2r[E_ + i] = hv;
    x2r[E_ + H_ + i] = ctx[(size_t)n * H_ + i];
  }
}

// per-row max and log-sum-exp over V. grid N, block 256.
__global__ __launch_bounds__(256) void rowstats_k(
    const float* __restrict__ lg, float* __restrict__ rmax, float* __restrict__ rlse)
{
  __shared__ float red[256];
  const int n = blockIdx.x, tid = threadIdx.x;
  const float* row = lg + (size_t)n * V_;
  float mx = -3.4e38f;
  for (int v = tid; v < V_; v += 256) mx = fmaxf(mx, row[v]);
  red[tid] = mx; __syncthreads();
  for (int s = 128; s; s >>= 1) {
    if (tid < s) red[tid] = fmaxf(red[tid], red[tid + s]);
    __syncthreads();
  }
  mx = red[0]; __syncthreads();
  float sm = 0.f;
  for (int v = tid; v < V_; v += 256) sm += expf(row[v] - mx);
  red[tid] = sm; __syncthreads();
  for (int s = 128; s; s >>= 1) {
    if (tid < s) red[tid] += red[tid + s];
    __syncthreads();
  }
  if (tid == 0) { rmax[n] = mx; rlse[n] = logf(red[0]); }
}

// ---- top-k helpers (K=3, jax tie-break: value desc, then smaller index) ----
__device__ __forceinline__ bool tk_better(float va, int ia, float vb, int ib) {
  return (va > vb) || (va == vb && ia < ib);
}
__device__ __forceinline__ void tk_insert(float v, int i, float* vv, int* ii) {
  if (tk_better(v, i, vv[0], ii[0])) {
    vv[2] = vv[1]; ii[2] = ii[1]; vv[1] = vv[0]; ii[1] = ii[0]; vv[0] = v; ii[0] = i;
  } else if (tk_better(v, i, vv[1], ii[1])) {
    vv[2] = vv[1]; ii[2] = ii[1]; vv[1] = v; ii[1] = i;
  } else if (tk_better(v, i, vv[2], ii[2])) {
    vv[2] = v; ii[2] = i;
  }
}
// block-level top-3 reduce over per-thread sorted triples in LDS
__device__ __forceinline__ void tk_block_reduce(float* sv, int* si, int tid) {
  for (int str = 128; str; str >>= 1) {
    if (tid < str) {
      float av[3], bv[3], rv[3];
      int ai[3], bi[3], ri[3];
#pragma unroll
      for (int q = 0; q < 3; q++) {
        av[q] = sv[tid * 3 + q];          ai[q] = si[tid * 3 + q];
        bv[q] = sv[(tid + str) * 3 + q];  bi[q] = si[(tid + str) * 3 + q];
      }
      int p = 0, q = 0;
#pragma unroll
      for (int t = 0; t < 3; t++) {
        bool ta = (q >= 3) || (p < 3 && tk_better(av[p], ai[p], bv[q], bi[q]));
        if (ta) { rv[t] = av[p]; ri[t] = ai[p]; p++; }
        else    { rv[t] = bv[q]; ri[t] = bi[q]; q++; }
      }
#pragma unroll
      for (int t = 0; t < 3; t++) { sv[tid * 3 + t] = rv[t]; si[tid * 3 + t] = ri[t]; }
    }
    __syncthreads();
  }
}

// step-0 top-k over V per batch. grid B, block 256.
__global__ __launch_bounds__(256) void topk0_k(
    const float* __restrict__ lg, const float* __restrict__ rmax,
    const float* __restrict__ rlse, float* __restrict__ cum,
    int* __restrict__ tok, int* __restrict__ eos, int* __restrict__ preds)
{
  __shared__ float sv[768];
  __shared__ int si[768];
  const int b = blockIdx.x, tid = threadIdx.x;
  float vv[3] = {-3.4e38f, -3.4e38f, -3.4e38f};
  int ii[3] = {0x7fffffff, 0x7fffffff, 0x7fffffff};
  const float mx = rmax[b], ls = rlse[b];
  const float* row = lg + (size_t)b * V_;
  for (int v = tid; v < V_; v += 256)
    tk_insert(row[v] - mx - ls, v, vv, ii);
#pragma unroll
  for (int t = 0; t < 3; t++) { sv[tid * 3 + t] = vv[t]; si[tid * 3 + t] = ii[t]; }
  __syncthreads();
  tk_block_reduce(sv, si, tid);
  if (tid < 3) {
    int n = b * K_ + tid;
    float val = sv[tid]; int idx = si[tid];
    cum[n] = val; tok[n] = idx; eos[n] = (idx == EOS_) ? 1 : 0;
    preds[n] = idx;   // row 0
  }
}

// step-t top-k over K*V per batch. grid B, block 256.
__global__ __launch_bounds__(256) void topk1_k(
    const float* __restrict__ lg, const float* __restrict__ rmax,
    const float* __restrict__ rlse, const float* __restrict__ cum,
    const int* __restrict__ eos, float* __restrict__ tkv, int* __restrict__ tki)
{
  __shared__ float sv[768];
  __shared__ int si[768];
  __shared__ float scum[3], smx[3], sls[3];
  __shared__ int seos[3];
  const int b = blockIdx.x, tid = threadIdx.x;
  if (tid < 3) {
    int n = b * K_ + tid;
    scum[tid] = cum[n]; smx[tid] = rmax[n]; sls[tid] = rlse[n]; seos[tid] = eos[n];
  }
  __syncthreads();
  float vv[3] = {-3.4e38f, -3.4e38f, -3.4e38f};
  int ii[3] = {0x7fffffff, 0x7fffffff, 0x7fffffff};
  for (int j = tid; j < K_ * V_; j += 256) {
    int k = (j >= 2 * V_) ? 2 : ((j >= V_) ? 1 : 0);
    int v = j - k * V_;
    float val;
    if (seos[k]) val = scum[k] + ((v == EOS_) ? 0.f : NEG_);
    else         val = scum[k] + (lg[((size_t)b * K_ + k) * V_ + v] - smx[k] - sls[k]);
    tk_insert(val, j, vv, ii);
  }
#pragma unroll
  for (int t = 0; t < 3; t++) { sv[tid * 3 + t] = vv[t]; si[tid * 3 + t] = ii[t]; }
  __syncthreads();
  tk_block_reduce(sv, si, tid);
  if (tid < 3) { tkv[b * K_ + tid] = sv[tid]; tki[b * K_ + tid] = si[tid]; }
}

// step-0 beam expansion: h[n]=h2[n/3], c[n]=c2[n/3]. grid 96, block 256.
__global__ __launch_bounds__(256) void reorder0_k(
    const float* __restrict__ h2, const float* __restrict__ c2,
    float* __restrict__ h, float* __restrict__ c)
{
  const int n = blockIdx.x, bsrc = n / K_, tid = threadIdx.x;
  for (int i = tid; i < H_; i += 256) {
    h[(size_t)n * H_ + i] = h2[(size_t)bsrc * H_ + i];
    c[(size_t)n * H_ + i] = c2[(size_t)bsrc * H_ + i];
  }
}

// step-t gather/update. grid 96, block 256.
__global__ __launch_bounds__(256) void reorder1_k(
    const float* __restrict__ h2, const float* __restrict__ c2,
    float* __restrict__ h, float* __restrict__ c,
    const int* __restrict__ tki, const float* __restrict__ tkv,
    float* __restrict__ cum, const int* __restrict__ eosOld,
    int* __restrict__ eosNew, const int* __restrict__ pOld,
    int* __restrict__ pNew, int* __restrict__ tok, int t)
{
  const int n = blockIdx.x, tid = threadIdx.x;
  const int b = n / K_;
  const int j = tki[n];
  const int beam = (j >= 2 * V_) ? 2 : ((j >= V_) ? 1 : 0);
  const int ntok = j - beam * V_;
  const int g = b * K_ + beam;
  for (int i = tid; i < H_; i += 256) {
    h[(size_t)n * H_ + i] = h2[(size_t)g * H_ + i];
    c[(size_t)n * H_ + i] = c2[(size_t)g * H_ + i];
  }
  if (tid < T_) pNew[tid * N1_ + n] = (tid == t) ? ntok : pOld[tid * N1_ + g];
  if (tid == 0) {
    cum[n] = tkv[n];
    eosNew[n] = eosOld[g] | (ntok == EOS_ ? 1 : 0);
    tok[n] = ntok;
  }
}

// final: out[0:1024] = preds[t][b*K] (as float), out[1024:1120] = cum.
__global__ __launch_bounds__(256) void finalout_k(
    const int* __restrict__ preds, const float* __restrict__ cum,
    float* __restrict__ out)
{
  const int i = blockIdx.x * 256 + threadIdx.x;
  if (i < T_ * B_) {
    int t = i >> 5, b = i & 31;
    out[i] = (float)preds[t * N1_ + b * K_];
  } else if (i < T_ * B_ + N1_) {
    out[i] = cum[i - T_ * B_];
  }
}

// ---------------------------------------------------------------------------
extern "C" void kernel_launch(void* const* d_in, const int* in_sizes, int n_in,
                              void* d_out, int out_size, void* d_ws, size_t ws_size,
                              hipStream_t stream)
{
  const float* enc    = (const float*)d_in[0];   // (S,B,H)
  const float* last_h = (const float*)d_in[1];   // (2,B,H)
  const float* last_c = (const float*)d_in[2];   // (2,B,H)
  const float* mask   = (const float*)d_in[3];   // (B,S)
  // d_in[4] = indices (unused)
  const float* emb    = (const float*)d_in[5];   // (V,E)
  const float* Wp     = (const float*)d_in[6];   // (H,H)
  const float* We     = (const float*)d_in[7];   // (H,H)
  const float* Wv     = (const float*)d_in[8];   // (H,)
  const float* W_ih   = (const float*)d_in[9];   // (768,2048)
  const float* W_hh   = (const float*)d_in[10];  // (512,2048)
  const float* b_ih   = (const float*)d_in[11];  // (2048,)
  const float* b_hh   = (const float*)d_in[12];  // (2048,)
  const float* Wc     = (const float*)d_in[13];  // (1280,V)
  const float* bc     = (const float*)d_in[14];  // (V,)
  const float* W_init = (const float*)d_in[15];  // (H,H)
  const float* b_init = (const float*)d_in[16];  // (H,)

  // workspace carve (floats)
  float* w = (float*)d_ws;
  float* encp = w;                 w += (size_t)S_ * B_ * H_;   // 4,194,304
  float* h    = w;                 w += N1_ * H_;
  float* c    = w;                 w += N1_ * H_;
  float* h2   = w;                 w += N1_ * H_;
  float* c2   = w;                 w += N1_ * H_;
  float* pp   = w;                 w += N1_ * H_;
  float* ctx  = w;                 w += N1_ * H_;
  float* sc   = w;                 w += N1_ * S_;
  float* xcat = w;                 w += N1_ * 1280;
  float* x2   = w;                 w += N1_ * 1280;
  float* gts  = w;                 w += N1_ * 4 * H_;
  float* lg   = w;                 w += (size_t)N1_ * V_;       // 960,000
  float* rmax = w;                 w += N1_;
  float* rlse = w;                 w += N1_;
  float* cum  = w;                 w += N1_;
  float* tkv  = w;                 w += N1_;
  int* tki  = (int*)w;             w += N1_;
  int* tok  = (int*)w;             w += N1_;
  int* eosA = (int*)w;             w += N1_;
  int* eosB = (int*)w;             w += N1_;
  int* pA   = (int*)w;             w += T_ * N1_;
  int* pB   = (int*)w;             w += T_ * N1_;

  // ---- prologue ----
  // h0 = last_h[1] @ W_init + b_init ; c0 likewise
  gemm_k<<<dim3(8, 1), 256, 0, stream>>>(last_h + B_ * H_, W_init, nullptr, H_,
                                         b_init, nullptr, h, B_, H_, H_);
  gemm_k<<<dim3(8, 1), 256, 0, stream>>>(last_c + B_ * H_, W_init, nullptr, H_,
                                         b_init, nullptr, c, B_, H_, H_);
  // enc_proj = encoder_states @ We   (8192 x 512 x 512)
  gemm_k<<<dim3(8, 128), 256, 0, stream>>>(enc, We, nullptr, H_,
                                           nullptr, nullptr, encp, S_ * B_, H_, H_);

  // ---- step 0 (N=32, bdiv=1) ----
  gemm_k<<<dim3(8, 1), 256, 0, stream>>>(h, Wp, nullptr, H_, nullptr, nullptr,
                                         pp, B_, H_, H_);
  score_k<<<dim3(8, B_), 256, 0, stream>>>(pp, encp, Wv, mask, sc, 1);
  softmax_k<<<B_, 256, 0, stream>>>(sc);
  ctx_k<<<dim3(2, B_), 256, 0, stream>>>(sc, enc, ctx, 1);
  xcat_k<<<B_, 256, 0, stream>>>(emb, tok, ctx, h, xcat, 1);
  gemm_k<<<dim3(32, 1), 256, 0, stream>>>(xcat, W_ih, W_hh, 768, b_ih, b_hh,
                                          gts, B_, 1280, 4 * H_);
  lstm_k<<<B_, 256, 0, stream>>>(gts, c, ctx, xcat, h2, c2, x2);
  gemm_k<<<dim3(157, 1), 256, 0, stream>>>(x2, Wc, nullptr, 1280, bc, nullptr,
                                           lg, B_, 1280, V_);
  rowstats_k<<<B_, 256, 0, stream>>>(lg, rmax, rlse);
  topk0_k<<<B_, 256, 0, stream>>>(lg, rmax, rlse, cum, tok, eosA, pA);
  reorder0_k<<<N1_, 256, 0, stream>>>(h2, c2, h, c);

  // ---- steps 1..31 (N=96, bdiv=3) ----
  for (int t = 1; t < T_; t++) {
    int* eosOld = (t & 1) ? eosA : eosB;
    int* eosNew = (t & 1) ? eosB : eosA;
    int* pOld   = (t & 1) ? pA : pB;
    int* pNew   = (t & 1) ? pB : pA;
    gemm_k<<<dim3(8, 2), 256, 0, stream>>>(h, Wp, nullptr, H_, nullptr, nullptr,
                                           pp, N1_, H_, H_);
    score_k<<<dim3(8, N1_), 256, 0, stream>>>(pp, encp, Wv, mask, sc, K_);
    softmax_k<<<N1_, 256, 0, stream>>>(sc);
    ctx_k<<<dim3(2, N1_), 256, 0, stream>>>(sc, enc, ctx, K_);
    xcat_k<<<N1_, 256, 0, stream>>>(emb, tok, ctx, h, xcat, 0);
    gemm_k<<<dim3(32, 2), 256, 0, stream>>>(xcat, W_ih, W_hh, 768, b_ih, b_hh,
                                            gts, N1_, 1280, 4 * H_);
    lstm_k<<<N1_, 256, 0, stream>>>(gts, c, ctx, xcat, h2, c2, x2);
    gemm_k<<<dim3(157, 2), 256, 0, stream>>>(x2, Wc, nullptr, 1280, bc, nullptr,
                                             lg, N1_, 1280, V_);
    rowstats_k<<<N1_, 256, 0, stream>>>(lg, rmax, rlse);
    topk1_k<<<B_, 256, 0, stream>>>(lg, rmax, rlse, cum, eosOld, tkv, tki);
    reorder1_k<<<N1_, 256, 0, stream>>>(h2, c2, h, c, tki, tkv, cum,
                                        eosOld, eosNew, pOld, pNew, tok, t);
  }

  // final preds buffer: t=31 is odd -> pB
  finalout_k<<<5, 256, 0, stream>>>(pB, cum, (float*)d_out);
}

// Round 3
// 11078.519 us; speedup vs baseline: 1.0990x; 1.0990x over previous
//
#include <hip/hip_runtime.h>
#include <hip/hip_bf16.h>
#include <math.h>

#define S_   256
#define B_   32
#define H_   512
#define E_   256
#define V_   10000
#define K_   3
#define T_   32
#define N1_  96
#define BOS_ 1
#define EOS_ 1
#define NEG_ (-1000000000.0f)
#define RT   4      // per-row top-RT kept for exact beam merge (RT > K suffices)

// ---------------------------------------------------------------------------
// fp32 tiled GEMM, 64x64 tile, TK=16, 256 threads, 4x4 thread tile,
// register-prefetch double buffering, optional split-K (blockIdx.z).
// C_part(z)[n][m] = sum_{k in part z} A[n][k]*Brow(k)[m]  (+bias on z==0)
// Brow(k) = B1 + k*M for k < split else B2 + (k-split)*M.
// ---------------------------------------------------------------------------
__global__ __launch_bounds__(256) void gemm_k(
    const float* __restrict__ A, const float* __restrict__ B1,
    const float* __restrict__ B2, int split,
    const float* __restrict__ bias1, const float* __restrict__ bias2,
    float* __restrict__ C, int N, int Kd, int M, int klen, size_t cstride)
{
  __shared__ float As[16][64];
  __shared__ float Bs[16][64];
  const int tid = threadIdx.x;
  const int m0 = blockIdx.x * 64;
  const int n0 = blockIdx.y * 64;
  const int kstart = blockIdx.z * klen;
  const int kend = kstart + klen;
  const int tm = tid & 15, tn = tid >> 4;
  const int la_n = tid & 63;
  const int la_k = (tid >> 6) * 4;
  const int lb_m = (tid & 15) * 4;
  const int lb_k = tid >> 4;

  const int an = (n0 + la_n < N) ? (n0 + la_n) : 0;   // clamp (store guarded)
  const float* Arow = A + (size_t)an * Kd;

  float* Cpart = C + (size_t)blockIdx.z * cstride;

  float4 a_reg, b_reg;
  a_reg = *(const float4*)(Arow + kstart + la_k);
  {
    int krow = kstart + lb_k;
    const float* Brow = (krow < split) ? (B1 + (size_t)krow * M)
                                       : (B2 + (size_t)(krow - split) * M);
    int m = m0 + lb_m;
    if (m + 3 < M) b_reg = *(const float4*)(Brow + m);
    else {
      b_reg.x = (m + 0 < M) ? Brow[m + 0] : 0.f;
      b_reg.y = (m + 1 < M) ? Brow[m + 1] : 0.f;
      b_reg.z = (m + 2 < M) ? Brow[m + 2] : 0.f;
      b_reg.w = (m + 3 < M) ? Brow[m + 3] : 0.f;
    }
  }

  float acc[4][4] = {};

  for (int k0 = kstart; k0 < kend; k0 += 16) {
    if (k0 > kstart) __syncthreads();
    As[la_k + 0][la_n] = a_reg.x; As[la_k + 1][la_n] = a_reg.y;
    As[la_k + 2][la_n] = a_reg.z; As[la_k + 3][la_n] = a_reg.w;
    *(float4*)&Bs[lb_k][lb_m] = b_reg;
    __syncthreads();
    if (k0 + 16 < kend) {
      a_reg = *(const float4*)(Arow + (k0 + 16) + la_k);
      int krow = k0 + 16 + lb_k;
      const float* Brow = (krow < split) ? (B1 + (size_t)krow * M)
                                         : (B2 + (size_t)(krow - split) * M);
      int m = m0 + lb_m;
      if (m + 3 < M) b_reg = *(const float4*)(Brow + m);
      else {
        b_reg.x = (m + 0 < M) ? Brow[m + 0] : 0.f;
        b_reg.y = (m + 1 < M) ? Brow[m + 1] : 0.f;
        b_reg.z = (m + 2 < M) ? Brow[m + 2] : 0.f;
        b_reg.w = (m + 3 < M) ? Brow[m + 3] : 0.f;
      }
    }
#pragma unroll
    for (int kk = 0; kk < 16; kk++) {
      float4 av = *(const float4*)&As[kk][tn * 4];
      float4 bv = *(const float4*)&Bs[kk][tm * 4];
      float a[4] = {av.x, av.y, av.z, av.w};
      float b[4] = {bv.x, bv.y, bv.z, bv.w};
#pragma unroll
      for (int i = 0; i < 4; i++)
#pragma unroll
        for (int j = 0; j < 4; j++) acc[i][j] += a[i] * b[j];
    }
  }

  const bool addBias = (blockIdx.z == 0);
#pragma unroll
  for (int i = 0; i < 4; i++) {
    int n = n0 + tn * 4 + i;
    if (n >= N) continue;
#pragma unroll
    for (int j = 0; j < 4; j++) {
      int m = m0 + tm * 4 + j;
      if (m >= M) continue;
      float v = acc[i][j];
      if (addBias && bias1) v += bias1[m];
      if (addBias && bias2) v += bias2[m];
      Cpart[(size_t)n * M + m] = v;
    }
  }
}

// ---------------------------------------------------------------------------
// Fused attention: pp = h@Wp (inline GEMV) -> score(tanh dot Wv, masked)
// -> softmax -> ctx -> xcat = [ex | ctx | hprev].
// grid N blocks, 512 threads.
// ---------------------------------------------------------------------------
__global__ __launch_bounds__(512) void attn_k(
    const float* __restrict__ h, const float* __restrict__ Wp,
    const float* __restrict__ encp, const float* __restrict__ enc,
    const float* __restrict__ Wv, const float* __restrict__ mask,
    const float* __restrict__ emb, const int* __restrict__ tok,
    float* __restrict__ xcat, int bdiv, int tok_is_bos)
{
  __shared__ float hS[512];
  __shared__ float ppS[512];
  __shared__ float WvS[512];
  __shared__ float aS[256];
  __shared__ float scr[512];
  const int n = blockIdx.x, tid = threadIdx.x;
  const int b = n / bdiv;
  hS[tid] = h[(size_t)n * H_ + tid];
  WvS[tid] = Wv[tid];
  __syncthreads();
  // pp[tid] = sum_k hS[k] * Wp[k][tid]
  {
    float acc = 0.f;
#pragma unroll 4
    for (int k = 0; k < H_; k++) acc += hS[k] * Wp[(size_t)k * H_ + tid];
    ppS[tid] = acc;
  }
  __syncthreads();
  const int w = tid >> 6, lane = tid & 63;
  for (int s2 = 0; s2 < 32; s2++) {
    int s = w * 32 + s2;
    const float* ep = encp + ((size_t)s * B_ + b) * H_;
    float acc = 0.f;
#pragma unroll
    for (int r = 0; r < 8; r++) {
      int hh = r * 64 + lane;
      acc += tanhf(ppS[hh] + ep[hh]) * WvS[hh];
    }
#pragma unroll
    for (int off = 32; off; off >>= 1) acc += __shfl_xor(acc, off);
    if (lane == 0)
      aS[s] = (mask[(size_t)b * S_ + s] == 0.f) ? NEG_ : acc;
  }
  __syncthreads();
  float v = (tid < 256) ? aS[tid] : -3.4e38f;
  scr[tid] = v; __syncthreads();
  for (int st = 256; st; st >>= 1) {
    if (tid < st) scr[tid] = fmaxf(scr[tid], scr[tid + st]);
    __syncthreads();
  }
  float mx = scr[0]; __syncthreads();
  float e = (tid < 256) ? expf(v - mx) : 0.f;
  scr[tid] = e; __syncthreads();
  for (int st = 256; st; st >>= 1) {
    if (tid < st) scr[tid] += scr[tid + st];
    __syncthreads();
  }
  if (tid < 256) aS[tid] = e / scr[0];
  __syncthreads();
  // ctx[h=tid] = sum_s a[s] * enc[s][b][tid]
  const float* ecol = enc + (size_t)b * H_ + tid;
  float acc = 0.f;
#pragma unroll 4
  for (int s = 0; s < 256; s++) acc += aS[s] * ecol[(size_t)s * (B_ * H_)];
  float* xr = xcat + (size_t)n * 1280;
  xr[E_ + tid] = acc;            // ctx  [256, 768)
  xr[E_ + H_ + tid] = hS[tid];   // hprev[768, 1280)
  if (tid < E_) {
    int tk = tok_is_bos ? BOS_ : tok[n];
    xr[tid] = emb[(size_t)tk * E_ + tid];
  }
}

__device__ __forceinline__ float sigf(float x) { return 1.f / (1.f + expf(-x)); }

// LSTM pointwise; rewrites xcat row in place: [ex|ctx|hprev] -> [ex|h2|ctx].
// Per-thread RAW on xr[256+i] is same-thread (read ctx before write h2). grid N.
__global__ __launch_bounds__(256) void lstm_k(
    const float* __restrict__ gts, const float* __restrict__ cprev,
    float* __restrict__ xcat, float* __restrict__ h2, float* __restrict__ c2)
{
  const int n = blockIdx.x, tid = threadIdx.x;
  const float* g = gts + (size_t)n * (4 * H_);
  float* xr = xcat + (size_t)n * 1280;
  for (int i = tid; i < H_; i += 256) {
    float ctx_i = xr[E_ + i];                 // old ctx (this thread owns slot)
    float gi = g[i], gf = g[H_ + i], gg = g[2 * H_ + i], go = g[3 * H_ + i];
    float cc = cprev[(size_t)n * H_ + i];
    float cv = sigf(gf) * cc + sigf(gi) * tanhf(gg);
    float hv = sigf(go) * tanhf(cv);
    c2[(size_t)n * H_ + i] = cv;
    h2[(size_t)n * H_ + i] = hv;
    xr[E_ + i] = hv;                          // h2   [256, 768)
    xr[E_ + H_ + i] = ctx_i;                  // ctx  [768, 1280)
  }
}

// ---- top-k helpers (jax tie-break: value desc, then smaller index) ----
__device__ __forceinline__ bool tk_better(float va, int ia, float vb, int ib) {
  return (va > vb) || (va == vb && ia < ib);
}
__device__ __forceinline__ void tk_insertN(float v, int i, float* vv, int* ii) {
  if (!tk_better(v, i, vv[RT - 1], ii[RT - 1])) return;
  vv[RT - 1] = v; ii[RT - 1] = i;
#pragma unroll
  for (int q = RT - 1; q > 0; q--) {
    if (tk_better(vv[q], ii[q], vv[q - 1], ii[q - 1])) {
      float tv = vv[q]; vv[q] = vv[q - 1]; vv[q - 1] = tv;
      int ti = ii[q]; ii[q] = ii[q - 1]; ii[q - 1] = ti;
    }
  }
}
__device__ __forceinline__ void tk_merge(float* sv, int* si, int a, int b) {
  float rv[RT]; int ri[RT];
  int p = 0, q = 0;
#pragma unroll
  for (int t = 0; t < RT; t++) {
    bool ta;
    if (p >= RT) ta = false;
    else if (q >= RT) ta = true;
    else ta = tk_better(sv[a + p], si[a + p], sv[b + q], si[b + q]);
    if (ta) { rv[t] = sv[a + p]; ri[t] = si[a + p]; p++; }
    else    { rv[t] = sv[b + q]; ri[t] = si[b + q]; q++; }
  }
#pragma unroll
  for (int t = 0; t < RT; t++) { sv[a + t] = rv[t]; si[a + t] = ri[t]; }
}

// Per-row top-RT of raw logits + row max + lse. grid = Nrows, 256 threads.
__global__ __launch_bounds__(256) void rowtop_k(
    const float* __restrict__ lgA, const float* __restrict__ lgB, int two,
    float* __restrict__ rtv, int* __restrict__ rti,
    float* __restrict__ rmax, float* __restrict__ rlse)
{
  __shared__ float sv[256 * RT];
  __shared__ int si[256 * RT];
  __shared__ float red[256];
  const int n = blockIdx.x, tid = threadIdx.x;
  const float* ra = lgA + (size_t)n * V_;
  const float* rb = lgB + (size_t)n * V_;
  float vv[RT]; int ii[RT];
#pragma unroll
  for (int q = 0; q < RT; q++) { vv[q] = -3.4e38f; ii[q] = 0x7fffffff; }
  if (two) {
    for (int v = tid; v < V_; v += 256) tk_insertN(ra[v] + rb[v], v, vv, ii);
  } else {
    for (int v = tid; v < V_; v += 256) tk_insertN(ra[v], v, vv, ii);
  }
#pragma unroll
  for (int q = 0; q < RT; q++) { sv[tid * RT + q] = vv[q]; si[tid * RT + q] = ii[q]; }
  __syncthreads();
  for (int st = 128; st; st >>= 1) {
    if (tid < st) tk_merge(sv, si, tid * RT, (tid + st) * RT);
    __syncthreads();
  }
  const float mx = sv[0];
  float sm = 0.f;
  if (two) {
    for (int v = tid; v < V_; v += 256) sm += expf(ra[v] + rb[v] - mx);
  } else {
    for (int v = tid; v < V_; v += 256) sm += expf(ra[v] - mx);
  }
  red[tid] = sm; __syncthreads();
  for (int st = 128; st; st >>= 1) {
    if (tid < st) red[tid] += red[tid + st];
    __syncthreads();
  }
  if (tid < RT) { rtv[n * RT + tid] = sv[tid]; rti[n * RT + tid] = si[tid]; }
  if (tid == 0) { rmax[n] = mx; rlse[n] = logf(red[0]); }
}

// step-0: beam expand + init cum/tok/eos/preds from per-row top-RT. grid 96.
__global__ __launch_bounds__(256) void reorder0_k(
    const float* __restrict__ h2, const float* __restrict__ c2,
    float* __restrict__ h, float* __restrict__ c,
    const float* __restrict__ rtv, const int* __restrict__ rti,
    const float* __restrict__ rmax, const float* __restrict__ rlse,
    float* __restrict__ cum, int* __restrict__ eos, int* __restrict__ tok,
    int* __restrict__ preds)
{
  const int n = blockIdx.x, b = n / K_, r = n % K_, tid = threadIdx.x;
  for (int i = tid; i < H_; i += 256) {
    h[(size_t)n * H_ + i] = h2[(size_t)b * H_ + i];
    c[(size_t)n * H_ + i] = c2[(size_t)b * H_ + i];
  }
  if (tid < T_) preds[tid * N1_ + n] = 0;
  if (tid == 0) {
    float val = (rtv[b * RT + r] - rmax[b]) - rlse[b];
    int idx = rti[b * RT + r];
    preds[n] = idx;
    cum[n] = val; tok[n] = idx; eos[n] = (idx == EOS_) ? 1 : 0;
  }
}

// step-t: 12-candidate exact merge + gather h/c/preds. grid 96.
__global__ __launch_bounds__(256) void reorder1_k(
    const float* __restrict__ h2, const float* __restrict__ c2,
    float* __restrict__ h, float* __restrict__ c,
    const float* __restrict__ rtv, const int* __restrict__ rti,
    const float* __restrict__ rmax, const float* __restrict__ rlse,
    const float* __restrict__ cumOld, float* __restrict__ cumNew,
    const int* __restrict__ eosOld, int* __restrict__ eosNew,
    const int* __restrict__ pOld, int* __restrict__ pNew,
    int* __restrict__ tok, int t)
{
  __shared__ int s_g, s_tok;
  __shared__ float s_val;
  const int n = blockIdx.x, b = n / K_, r = n % K_, tid = threadIdx.x;
  if (tid == 0) {
    float cv[3 * RT]; int cj[3 * RT]; int cnt = 0;
    for (int k = 0; k < K_; k++) {
      int row = b * K_ + k;
      float ck = cumOld[row];
      if (eosOld[row]) {
        cv[cnt] = ck; cj[cnt] = k * V_ + EOS_; cnt++;
      } else {
        float mxk = rmax[row], lsk = rlse[row];
        for (int q = 0; q < RT; q++) {
          cv[cnt] = ck + ((rtv[row * RT + q] - mxk) - lsk);
          cj[cnt] = k * V_ + rti[row * RT + q]; cnt++;
        }
      }
    }
    int used = 0, pick = -1;
    for (int rep = 0; rep <= r; rep++) {
      pick = -1;
      for (int i2 = 0; i2 < cnt; i2++) {
        if ((used >> i2) & 1) continue;
        if (pick < 0 || tk_better(cv[i2], cj[i2], cv[pick], cj[pick])) pick = i2;
      }
      used |= 1 << pick;
    }
    int j = cj[pick];
    s_val = cv[pick];
    s_g = b * K_ + j / V_;
    s_tok = j % V_;
  }
  __syncthreads();
  const int g = s_g, ntok = s_tok;
  for (int i = tid; i < H_; i += 256) {
    h[(size_t)n * H_ + i] = h2[(size_t)g * H_ + i];
    c[(size_t)n * H_ + i] = c2[(size_t)g * H_ + i];
  }
  if (tid < T_) pNew[tid * N1_ + n] = (tid == t) ? ntok : pOld[tid * N1_ + g];
  if (tid == 0) {
    cumNew[n] = s_val;
    eosNew[n] = eosOld[g] | (ntok == EOS_ ? 1 : 0);
    tok[n] = ntok;
  }
}

// out[0:1024] = preds[t][b*K] (float), out[1024:1120] = cum.
__global__ __launch_bounds__(256) void finalout_k(
    const int* __restrict__ preds, const float* __restrict__ cum,
    float* __restrict__ out)
{
  const int i = blockIdx.x * 256 + threadIdx.x;
  if (i < T_ * B_) {
    int t = i >> 5, b = i & 31;
    out[i] = (float)preds[t * N1_ + b * K_];
  } else if (i < T_ * B_ + N1_) {
    out[i] = cum[i - T_ * B_];
  }
}

// ---------------------------------------------------------------------------
extern "C" void kernel_launch(void* const* d_in, const int* in_sizes, int n_in,
                              void* d_out, int out_size, void* d_ws, size_t ws_size,
                              hipStream_t stream)
{
  const float* enc    = (const float*)d_in[0];
  const float* last_h = (const float*)d_in[1];
  const float* last_c = (const float*)d_in[2];
  const float* mask   = (const float*)d_in[3];
  const float* emb    = (const float*)d_in[5];
  const float* Wp     = (const float*)d_in[6];
  const float* We     = (const float*)d_in[7];
  const float* Wv     = (const float*)d_in[8];
  const float* W_ih   = (const float*)d_in[9];
  const float* W_hh   = (const float*)d_in[10];
  const float* b_ih   = (const float*)d_in[11];
  const float* b_hh   = (const float*)d_in[12];
  const float* Wc     = (const float*)d_in[13];
  const float* bc     = (const float*)d_in[14];
  const float* W_init = (const float*)d_in[15];
  const float* b_init = (const float*)d_in[16];

  // ws carve — unconditional footprint 22,711,936 B (< round-1-proven 23.69 MB)
  float* w = (float*)d_ws;
  float* encp = w;  w += (size_t)S_ * B_ * H_;   // 4,194,304
  float* h    = w;  w += N1_ * H_;
  float* c    = w;  w += N1_ * H_;
  float* h2   = w;  w += N1_ * H_;
  float* c2   = w;  w += N1_ * H_;
  float* xcat = w;  w += N1_ * 1280;             // doubles as x2 (in-place LSTM)
  float* gts  = w;  w += N1_ * 4 * H_;
  float* rtv  = w;  w += N1_ * RT;
  float* rmax = w;  w += N1_;
  float* rlse = w;  w += N1_;
  float* cumA = w;  w += N1_;
  float* cumB = w;  w += N1_;
  int* rti  = (int*)w;  w += N1_ * RT;
  int* tok  = (int*)w;  w += N1_;
  int* eosA = (int*)w;  w += N1_;
  int* eosB = (int*)w;  w += N1_;
  int* pA   = (int*)w;  w += T_ * N1_;
  int* pB   = (int*)w;  w += T_ * N1_;
  const size_t lgN = (size_t)N1_ * V_;
  float* lgA = w;  w += lgN;
  float* lgB = w;   // used only if it fits inside ws
  const int kparts_lg =
      (((char*)(w + lgN) - (char*)d_ws) <= (ptrdiff_t)ws_size) ? 2 : 1;

  // ---- prologue ----
  gemm_k<<<dim3(8, 1, 1), 256, 0, stream>>>(last_h + B_ * H_, W_init, nullptr, H_,
      b_init, nullptr, h, B_, H_, H_, H_, 0);
  gemm_k<<<dim3(8, 1, 1), 256, 0, stream>>>(last_c + B_ * H_, W_init, nullptr, H_,
      b_init, nullptr, c, B_, H_, H_, H_, 0);
  gemm_k<<<dim3(8, 128, 1), 256, 0, stream>>>(enc, We, nullptr, H_,
      nullptr, nullptr, encp, S_ * B_, H_, H_, H_, 0);

  for (int t = 0; t < T_; t++) {
    const int N = (t == 0) ? B_ : N1_;
    const int ntiles = (t == 0) ? 1 : 2;
    const int bdiv = (t == 0) ? 1 : K_;

    attn_k<<<N, 512, 0, stream>>>(h, Wp, encp, enc, Wv, mask, emb, tok,
        xcat, bdiv, t == 0 ? 1 : 0);
    gemm_k<<<dim3(32, ntiles, 1), 256, 0, stream>>>(xcat, W_ih, W_hh, E_ + H_,
        b_ih, b_hh, gts, N, 1280, 4 * H_, 1280, 0);
    lstm_k<<<N, 256, 0, stream>>>(gts, c, xcat, h2, c2);
    gemm_k<<<dim3(157, ntiles, kparts_lg), 256, 0, stream>>>(xcat, Wc, nullptr,
        1280, bc, nullptr, lgA, N, 1280, V_, 1280 / kparts_lg, lgN);
    rowtop_k<<<N, 256, 0, stream>>>(lgA, lgB, kparts_lg == 2 ? 1 : 0,
        rtv, rti, rmax, rlse);
    if (t == 0) {
      reorder0_k<<<N1_, 256, 0, stream>>>(h2, c2, h, c, rtv, rti, rmax, rlse,
          cumA, eosA, tok, pA);
    } else {
      float* cumOld = (t & 1) ? cumA : cumB;
      float* cumNew = (t & 1) ? cumB : cumA;
      int* eosOld = (t & 1) ? eosA : eosB;
      int* eosNew = (t & 1) ? eosB : eosA;
      int* pOld   = (t & 1) ? pA : pB;
      int* pNew   = (t & 1) ? pB : pA;
      reorder1_k<<<N1_, 256, 0, stream>>>(h2, c2, h, c, rtv, rti, rmax, rlse,
          cumOld, cumNew, eosOld, eosNew, pOld, pNew, tok, t);
    }
  }

  // t=31 odd -> preds in pB, cum in cumB
  finalout_k<<<5, 256, 0, stream>>>(pB, cumB, (float*)d_out);
}

// Round 4
// 6950.510 us; speedup vs baseline: 1.7517x; 1.5939x over previous
//
#include <hip/hip_runtime.h>
#include <hip/hip_bf16.h>
#include <math.h>

#define S_   256
#define B_   32
#define H_   512
#define E_   256
#define V_   10000
#define K_   3
#define T_   32
#define N1_  96
#define BOS_ 1
#define EOS_ 1
#define NEG_ (-1000000000.0f)
#define RT   4      // per-row top-RT kept for exact beam merge (RT > K suffices)

// ---------------------------------------------------------------------------
// fp32 tiled GEMM, 64x64 tile, TK=16, 256 threads, 4x4 thread tile,
// register-prefetch double buffering, optional split-K (blockIdx.z).
// ---------------------------------------------------------------------------
__global__ __launch_bounds__(256) void gemm_k(
    const float* __restrict__ A, const float* __restrict__ B1,
    const float* __restrict__ B2, int split,
    const float* __restrict__ bias1, const float* __restrict__ bias2,
    float* __restrict__ C, int N, int Kd, int M, int klen, size_t cstride)
{
  __shared__ float As[16][64];
  __shared__ float Bs[16][64];
  const int tid = threadIdx.x;
  const int m0 = blockIdx.x * 64;
  const int n0 = blockIdx.y * 64;
  const int kstart = blockIdx.z * klen;
  const int kend = kstart + klen;
  const int tm = tid & 15, tn = tid >> 4;
  const int la_n = tid & 63;
  const int la_k = (tid >> 6) * 4;
  const int lb_m = (tid & 15) * 4;
  const int lb_k = tid >> 4;

  const int an = (n0 + la_n < N) ? (n0 + la_n) : 0;   // clamp (store guarded)
  const float* Arow = A + (size_t)an * Kd;

  float* Cpart = C + (size_t)blockIdx.z * cstride;

  float4 a_reg, b_reg;
  a_reg = *(const float4*)(Arow + kstart + la_k);
  {
    int krow = kstart + lb_k;
    const float* Brow = (krow < split) ? (B1 + (size_t)krow * M)
                                       : (B2 + (size_t)(krow - split) * M);
    int m = m0 + lb_m;
    if (m + 3 < M) b_reg = *(const float4*)(Brow + m);
    else {
      b_reg.x = (m + 0 < M) ? Brow[m + 0] : 0.f;
      b_reg.y = (m + 1 < M) ? Brow[m + 1] : 0.f;
      b_reg.z = (m + 2 < M) ? Brow[m + 2] : 0.f;
      b_reg.w = (m + 3 < M) ? Brow[m + 3] : 0.f;
    }
  }

  float acc[4][4] = {};

  for (int k0 = kstart; k0 < kend; k0 += 16) {
    if (k0 > kstart) __syncthreads();
    As[la_k + 0][la_n] = a_reg.x; As[la_k + 1][la_n] = a_reg.y;
    As[la_k + 2][la_n] = a_reg.z; As[la_k + 3][la_n] = a_reg.w;
    *(float4*)&Bs[lb_k][lb_m] = b_reg;
    __syncthreads();
    if (k0 + 16 < kend) {
      a_reg = *(const float4*)(Arow + (k0 + 16) + la_k);
      int krow = k0 + 16 + lb_k;
      const float* Brow = (krow < split) ? (B1 + (size_t)krow * M)
                                         : (B2 + (size_t)(krow - split) * M);
      int m = m0 + lb_m;
      if (m + 3 < M) b_reg = *(const float4*)(Brow + m);
      else {
        b_reg.x = (m + 0 < M) ? Brow[m + 0] : 0.f;
        b_reg.y = (m + 1 < M) ? Brow[m + 1] : 0.f;
        b_reg.z = (m + 2 < M) ? Brow[m + 2] : 0.f;
        b_reg.w = (m + 3 < M) ? Brow[m + 3] : 0.f;
      }
    }
#pragma unroll
    for (int kk = 0; kk < 16; kk++) {
      float4 av = *(const float4*)&As[kk][tn * 4];
      float4 bv = *(const float4*)&Bs[kk][tm * 4];
      float a[4] = {av.x, av.y, av.z, av.w};
      float b[4] = {bv.x, bv.y, bv.z, bv.w};
#pragma unroll
      for (int i = 0; i < 4; i++)
#pragma unroll
        for (int j = 0; j < 4; j++) acc[i][j] += a[i] * b[j];
    }
  }

  const bool addBias = (blockIdx.z == 0);
#pragma unroll
  for (int i = 0; i < 4; i++) {
    int n = n0 + tn * 4 + i;
    if (n >= N) continue;
#pragma unroll
    for (int j = 0; j < 4; j++) {
      int m = m0 + tm * 4 + j;
      if (m >= M) continue;
      float v = acc[i][j];
      if (addBias && bias1) v += bias1[m];
      if (addBias && bias2) v += bias2[m];
      Cpart[(size_t)n * M + m] = v;
    }
  }
}

// ---------------------------------------------------------------------------
// pp[n][m0..m0+63] = sum_k h[n][k] * Wp[k][m].  grid (8, N), 256 thr.
// 4-way K-split per block (tid>>6), LDS reduce.
// ---------------------------------------------------------------------------
__global__ __launch_bounds__(256) void ppgemv_k(
    const float* __restrict__ h, const float* __restrict__ Wp,
    float* __restrict__ pp)
{
  __shared__ float hS[512];
  __shared__ float red[256];
  const int n = blockIdx.y, tid = threadIdx.x;
  const int m = blockIdx.x * 64 + (tid & 63);
  const int kg = tid >> 6;
  hS[tid] = h[(size_t)n * H_ + tid];
  hS[256 + tid] = h[(size_t)n * H_ + 256 + tid];
  __syncthreads();
  float acc = 0.f;
#pragma unroll 4
  for (int k = kg * 128; k < kg * 128 + 128; k++)
    acc += hS[k] * Wp[(size_t)k * H_ + m];
  red[tid] = acc;
  __syncthreads();
  if (tid < 64) {
    float v = red[tid] + red[64 + tid] + red[128 + tid] + red[192 + tid];
    pp[(size_t)n * H_ + blockIdx.x * 64 + tid] = v;
  }
}

// ---------------------------------------------------------------------------
// Raw masked scores sc[n][s] = dot(tanh(pp[n]+encp[s,b]), Wv) (NEG if masked).
// grid (8 s-tiles, N), 512 thr; wave w does s = stile*32 + w*4 + j.
// stile 0 also fills xcat[ex | .. | hprev].
// ---------------------------------------------------------------------------
__global__ __launch_bounds__(512) void score_k(
    const float* __restrict__ pp, const float* __restrict__ encp,
    const float* __restrict__ Wv, const float* __restrict__ mask,
    const float* __restrict__ emb, const int* __restrict__ tok,
    const float* __restrict__ h, float* __restrict__ sc,
    float* __restrict__ xcat, int bdiv, int tok_is_bos)
{
  __shared__ float ppS[512];
  __shared__ float WvS[512];
  const int n = blockIdx.y, tid = threadIdx.x;
  const int b = n / bdiv;
  ppS[tid] = pp[(size_t)n * H_ + tid];
  WvS[tid] = Wv[tid];
  if (blockIdx.x == 0) {
    xcat[(size_t)n * 1280 + E_ + H_ + tid] = h[(size_t)n * H_ + tid];  // hprev
    if (tid < E_) {
      int tk = tok_is_bos ? BOS_ : tok[n];
      xcat[(size_t)n * 1280 + tid] = emb[(size_t)tk * E_ + tid];       // ex
    }
  }
  __syncthreads();
  const int w = tid >> 6, lane = tid & 63;
#pragma unroll
  for (int j = 0; j < 4; j++) {
    int s = blockIdx.x * 32 + w * 4 + j;
    const float* ep = encp + ((size_t)s * B_ + b) * H_;
    float acc = 0.f;
#pragma unroll
    for (int r = 0; r < 8; r++) {
      int hh = r * 64 + lane;
      acc += tanhf(ppS[hh] + ep[hh]) * WvS[hh];
    }
#pragma unroll
    for (int off = 32; off; off >>= 1) acc += __shfl_xor(acc, off);
    if (lane == 0)
      sc[(size_t)n * S_ + s] = (mask[(size_t)b * S_ + s] == 0.f) ? NEG_ : acc;
  }
}

// ---------------------------------------------------------------------------
// ctx slice: softmax(sc[n]) recomputed in-block, then
// xcat[n][E_+h0+c] = sum_s a[s]*enc[s][b][h0+c].  grid (8 h-tiles, N), 256 thr.
// ---------------------------------------------------------------------------
__global__ __launch_bounds__(256) void ctx_k(
    const float* __restrict__ sc, const float* __restrict__ enc,
    float* __restrict__ xcat, int bdiv)
{
  __shared__ float aS[256];
  __shared__ float red[256];
  const int n = blockIdx.y, tid = threadIdx.x;
  const int b = n / bdiv;
  const int h0 = blockIdx.x * 64;
  float v = sc[(size_t)n * S_ + tid];
  red[tid] = v; __syncthreads();
  for (int st = 128; st; st >>= 1) {
    if (tid < st) red[tid] = fmaxf(red[tid], red[tid + st]);
    __syncthreads();
  }
  const float mx = red[0]; __syncthreads();
  float e = expf(v - mx);
  aS[tid] = e;
  red[tid] = e; __syncthreads();
  for (int st = 128; st; st >>= 1) {
    if (tid < st) red[tid] += red[tid + st];
    __syncthreads();
  }
  const float rsum = 1.f / red[0];
  __syncthreads();
  // s-loop: 4 s-groups x 64 columns
  const int sgrp = tid >> 6, col = tid & 63;
  float acc = 0.f;
#pragma unroll 4
  for (int s0 = 0; s0 < S_; s0 += 4) {
    int s = s0 + sgrp;
    acc += aS[s] * enc[((size_t)s * B_ + b) * H_ + h0 + col];
  }
  red[tid] = acc; __syncthreads();
  if (tid < 64) {
    float total = red[tid] + red[64 + tid] + red[128 + tid] + red[192 + tid];
    xcat[(size_t)n * 1280 + E_ + h0 + tid] = total * rsum;
  }
}

__device__ __forceinline__ float sigf(float x) { return 1.f / (1.f + expf(-x)); }

// LSTM pointwise; rewrites xcat row in place: [ex|ctx|hprev] -> [ex|h2|ctx].
__global__ __launch_bounds__(256) void lstm_k(
    const float* __restrict__ gts, const float* __restrict__ cprev,
    float* __restrict__ xcat, float* __restrict__ h2, float* __restrict__ c2)
{
  const int n = blockIdx.x, tid = threadIdx.x;
  const float* g = gts + (size_t)n * (4 * H_);
  float* xr = xcat + (size_t)n * 1280;
  for (int i = tid; i < H_; i += 256) {
    float ctx_i = xr[E_ + i];
    float gi = g[i], gf = g[H_ + i], gg = g[2 * H_ + i], go = g[3 * H_ + i];
    float cc = cprev[(size_t)n * H_ + i];
    float cv = sigf(gf) * cc + sigf(gi) * tanhf(gg);
    float hv = sigf(go) * tanhf(cv);
    c2[(size_t)n * H_ + i] = cv;
    h2[(size_t)n * H_ + i] = hv;
    xr[E_ + i] = hv;
    xr[E_ + H_ + i] = ctx_i;
  }
}

// ---- top-k helpers (jax tie-break: value desc, then smaller index) ----
__device__ __forceinline__ bool tk_better(float va, int ia, float vb, int ib) {
  return (va > vb) || (va == vb && ia < ib);
}
__device__ __forceinline__ void tk_insertN(float v, int i, float* vv, int* ii) {
  if (!tk_better(v, i, vv[RT - 1], ii[RT - 1])) return;
  vv[RT - 1] = v; ii[RT - 1] = i;
#pragma unroll
  for (int q = RT - 1; q > 0; q--) {
    if (tk_better(vv[q], ii[q], vv[q - 1], ii[q - 1])) {
      float tv = vv[q]; vv[q] = vv[q - 1]; vv[q - 1] = tv;
      int ti = ii[q]; ii[q] = ii[q - 1]; ii[q - 1] = ti;
    }
  }
}
__device__ __forceinline__ void tk_merge(float* sv, int* si, int a, int b) {
  float rv[RT]; int ri[RT];
  int p = 0, q = 0;
#pragma unroll
  for (int t = 0; t < RT; t++) {
    bool ta;
    if (p >= RT) ta = false;
    else if (q >= RT) ta = true;
    else ta = tk_better(sv[a + p], si[a + p], sv[b + q], si[b + q]);
    if (ta) { rv[t] = sv[a + p]; ri[t] = si[a + p]; p++; }
    else    { rv[t] = sv[b + q]; ri[t] = si[b + q]; q++; }
  }
#pragma unroll
  for (int t = 0; t < RT; t++) { sv[a + t] = rv[t]; si[a + t] = ri[t]; }
}

// Per-row top-RT of raw logits + row max + lse. grid = Nrows, 256 threads.
__global__ __launch_bounds__(256) void rowtop_k(
    const float* __restrict__ lgA, const float* __restrict__ lgB, int two,
    float* __restrict__ rtv, int* __restrict__ rti,
    float* __restrict__ rmax, float* __restrict__ rlse)
{
  __shared__ float sv[256 * RT];
  __shared__ int si[256 * RT];
  __shared__ float red[256];
  const int n = blockIdx.x, tid = threadIdx.x;
  const float* ra = lgA + (size_t)n * V_;
  const float* rb = lgB + (size_t)n * V_;
  float vv[RT]; int ii[RT];
#pragma unroll
  for (int q = 0; q < RT; q++) { vv[q] = -3.4e38f; ii[q] = 0x7fffffff; }
  if (two) {
    for (int v = tid; v < V_; v += 256) tk_insertN(ra[v] + rb[v], v, vv, ii);
  } else {
    for (int v = tid; v < V_; v += 256) tk_insertN(ra[v], v, vv, ii);
  }
#pragma unroll
  for (int q = 0; q < RT; q++) { sv[tid * RT + q] = vv[q]; si[tid * RT + q] = ii[q]; }
  __syncthreads();
  for (int st = 128; st; st >>= 1) {
    if (tid < st) tk_merge(sv, si, tid * RT, (tid + st) * RT);
    __syncthreads();
  }
  const float mx = sv[0];
  float sm = 0.f;
  if (two) {
    for (int v = tid; v < V_; v += 256) sm += expf(ra[v] + rb[v] - mx);
  } else {
    for (int v = tid; v < V_; v += 256) sm += expf(ra[v] - mx);
  }
  red[tid] = sm; __syncthreads();
  for (int st = 128; st; st >>= 1) {
    if (tid < st) red[tid] += red[tid + st];
    __syncthreads();
  }
  if (tid < RT) { rtv[n * RT + tid] = sv[tid]; rti[n * RT + tid] = si[tid]; }
  if (tid == 0) { rmax[n] = mx; rlse[n] = logf(red[0]); }
}

// step-0: beam expand + init cum/tok/eos/preds from per-row top-RT. grid 96.
__global__ __launch_bounds__(256) void reorder0_k(
    const float* __restrict__ h2, const float* __restrict__ c2,
    float* __restrict__ h, float* __restrict__ c,
    const float* __restrict__ rtv, const int* __restrict__ rti,
    const float* __restrict__ rmax, const float* __restrict__ rlse,
    float* __restrict__ cum, int* __restrict__ eos, int* __restrict__ tok,
    int* __restrict__ preds)
{
  const int n = blockIdx.x, b = n / K_, r = n % K_, tid = threadIdx.x;
  for (int i = tid; i < H_; i += 256) {
    h[(size_t)n * H_ + i] = h2[(size_t)b * H_ + i];
    c[(size_t)n * H_ + i] = c2[(size_t)b * H_ + i];
  }
  if (tid < T_) preds[tid * N1_ + n] = 0;
  if (tid == 0) {
    float val = (rtv[b * RT + r] - rmax[b]) - rlse[b];
    int idx = rti[b * RT + r];
    preds[n] = idx;
    cum[n] = val; tok[n] = idx; eos[n] = (idx == EOS_) ? 1 : 0;
  }
}

// step-t: 12-candidate exact merge + gather h/c/preds. grid 96.
__global__ __launch_bounds__(256) void reorder1_k(
    const float* __restrict__ h2, const float* __restrict__ c2,
    float* __restrict__ h, float* __restrict__ c,
    const float* __restrict__ rtv, const int* __restrict__ rti,
    const float* __restrict__ rmax, const float* __restrict__ rlse,
    const float* __restrict__ cumOld, float* __restrict__ cumNew,
    const int* __restrict__ eosOld, int* __restrict__ eosNew,
    const int* __restrict__ pOld, int* __restrict__ pNew,
    int* __restrict__ tok, int t)
{
  __shared__ int s_g, s_tok;
  __shared__ float s_val;
  const int n = blockIdx.x, b = n / K_, r = n % K_, tid = threadIdx.x;
  if (tid == 0) {
    float cv[3 * RT]; int cj[3 * RT]; int cnt = 0;
    for (int k = 0; k < K_; k++) {
      int row = b * K_ + k;
      float ck = cumOld[row];
      if (eosOld[row]) {
        cv[cnt] = ck; cj[cnt] = k * V_ + EOS_; cnt++;
      } else {
        float mxk = rmax[row], lsk = rlse[row];
        for (int q = 0; q < RT; q++) {
          cv[cnt] = ck + ((rtv[row * RT + q] - mxk) - lsk);
          cj[cnt] = k * V_ + rti[row * RT + q]; cnt++;
        }
      }
    }
    int used = 0, pick = -1;
    for (int rep = 0; rep <= r; rep++) {
      pick = -1;
      for (int i2 = 0; i2 < cnt; i2++) {
        if ((used >> i2) & 1) continue;
        if (pick < 0 || tk_better(cv[i2], cj[i2], cv[pick], cj[pick])) pick = i2;
      }
      used |= 1 << pick;
    }
    int j = cj[pick];
    s_val = cv[pick];
    s_g = b * K_ + j / V_;
    s_tok = j % V_;
  }
  __syncthreads();
  const int g = s_g, ntok = s_tok;
  for (int i = tid; i < H_; i += 256) {
    h[(size_t)n * H_ + i] = h2[(size_t)g * H_ + i];
    c[(size_t)n * H_ + i] = c2[(size_t)g * H_ + i];
  }
  if (tid < T_) pNew[tid * N1_ + n] = (tid == t) ? ntok : pOld[tid * N1_ + g];
  if (tid == 0) {
    cumNew[n] = s_val;
    eosNew[n] = eosOld[g] | (ntok == EOS_ ? 1 : 0);
    tok[n] = ntok;
  }
}

// out[0:1024] = preds[t][b*K] (float), out[1024:1120] = cum.
__global__ __launch_bounds__(256) void finalout_k(
    const int* __restrict__ preds, const float* __restrict__ cum,
    float* __restrict__ out)
{
  const int i = blockIdx.x * 256 + threadIdx.x;
  if (i < T_ * B_) {
    int t = i >> 5, b = i & 31;
    out[i] = (float)preds[t * N1_ + b * K_];
  } else if (i < T_ * B_ + N1_) {
    out[i] = cum[i - T_ * B_];
  }
}

// ---------------------------------------------------------------------------
extern "C" void kernel_launch(void* const* d_in, const int* in_sizes, int n_in,
                              void* d_out, int out_size, void* d_ws, size_t ws_size,
                              hipStream_t stream)
{
  const float* enc    = (const float*)d_in[0];
  const float* last_h = (const float*)d_in[1];
  const float* last_c = (const float*)d_in[2];
  const float* mask   = (const float*)d_in[3];
  const float* emb    = (const float*)d_in[5];
  const float* Wp     = (const float*)d_in[6];
  const float* We     = (const float*)d_in[7];
  const float* Wv     = (const float*)d_in[8];
  const float* W_ih   = (const float*)d_in[9];
  const float* W_hh   = (const float*)d_in[10];
  const float* b_ih   = (const float*)d_in[11];
  const float* b_hh   = (const float*)d_in[12];
  const float* Wc     = (const float*)d_in[13];
  const float* bc     = (const float*)d_in[14];
  const float* W_init = (const float*)d_in[15];
  const float* b_init = (const float*)d_in[16];

  // ws carve — unconditional footprint ~23.0 MB (< round-1-proven 23.69 MB)
  float* w = (float*)d_ws;
  float* encp = w;  w += (size_t)S_ * B_ * H_;   // 16.78 MB
  float* h    = w;  w += N1_ * H_;
  float* c    = w;  w += N1_ * H_;
  float* h2   = w;  w += N1_ * H_;
  float* c2   = w;  w += N1_ * H_;
  float* pp   = w;  w += N1_ * H_;
  float* sc   = w;  w += N1_ * S_;
  float* xcat = w;  w += N1_ * 1280;             // doubles as x2 (in-place LSTM)
  float* gts  = w;  w += N1_ * 4 * H_;
  float* rtv  = w;  w += N1_ * RT;
  float* rmax = w;  w += N1_;
  float* rlse = w;  w += N1_;
  float* cumA = w;  w += N1_;
  float* cumB = w;  w += N1_;
  int* rti  = (int*)w;  w += N1_ * RT;
  int* tok  = (int*)w;  w += N1_;
  int* eosA = (int*)w;  w += N1_;
  int* eosB = (int*)w;  w += N1_;
  int* pA   = (int*)w;  w += T_ * N1_;
  int* pB   = (int*)w;  w += T_ * N1_;
  const size_t lgN = (size_t)N1_ * V_;
  float* lgA = w;  w += lgN;
  float* lgB = w;   // used only if it fits inside ws
  const int kparts_lg =
      (((char*)(w + lgN) - (char*)d_ws) <= (ptrdiff_t)ws_size) ? 2 : 1;

  // ---- prologue ----
  gemm_k<<<dim3(8, 1, 1), 256, 0, stream>>>(last_h + B_ * H_, W_init, nullptr, H_,
      b_init, nullptr, h, B_, H_, H_, H_, 0);
  gemm_k<<<dim3(8, 1, 1), 256, 0, stream>>>(last_c + B_ * H_, W_init, nullptr, H_,
      b_init, nullptr, c, B_, H_, H_, H_, 0);
  gemm_k<<<dim3(8, 128, 1), 256, 0, stream>>>(enc, We, nullptr, H_,
      nullptr, nullptr, encp, S_ * B_, H_, H_, H_, 0);

  for (int t = 0; t < T_; t++) {
    const int N = (t == 0) ? B_ : N1_;
    const int ntiles = (t == 0) ? 1 : 2;
    const int bdiv = (t == 0) ? 1 : K_;

    ppgemv_k<<<dim3(8, N), 256, 0, stream>>>(h, Wp, pp);
    score_k<<<dim3(8, N), 512, 0, stream>>>(pp, encp, Wv, mask, emb, tok, h,
        sc, xcat, bdiv, t == 0 ? 1 : 0);
    ctx_k<<<dim3(8, N), 256, 0, stream>>>(sc, enc, xcat, bdiv);
    gemm_k<<<dim3(32, ntiles, 1), 256, 0, stream>>>(xcat, W_ih, W_hh, E_ + H_,
        b_ih, b_hh, gts, N, 1280, 4 * H_, 1280, 0);
    lstm_k<<<N, 256, 0, stream>>>(gts, c, xcat, h2, c2);
    gemm_k<<<dim3(157, ntiles, kparts_lg), 256, 0, stream>>>(xcat, Wc, nullptr,
        1280, bc, nullptr, lgA, N, 1280, V_, 1280 / kparts_lg, lgN);
    rowtop_k<<<N, 256, 0, stream>>>(lgA, lgB, kparts_lg == 2 ? 1 : 0,
        rtv, rti, rmax, rlse);
    if (t == 0) {
      reorder0_k<<<N1_, 256, 0, stream>>>(h2, c2, h, c, rtv, rti, rmax, rlse,
          cumA, eosA, tok, pA);
    } else {
      float* cumOld = (t & 1) ? cumA : cumB;
      float* cumNew = (t & 1) ? cumB : cumA;
      int* eosOld = (t & 1) ? eosA : eosB;
      int* eosNew = (t & 1) ? eosB : eosA;
      int* pOld   = (t & 1) ? pA : pB;
      int* pNew   = (t & 1) ? pB : pA;
      reorder1_k<<<N1_, 256, 0, stream>>>(h2, c2, h, c, rtv, rti, rmax, rlse,
          cumOld, cumNew, eosOld, eosNew, pOld, pNew, tok, t);
    }
  }

  // t=31 odd -> preds in pB, cum in cumB
  finalout_k<<<5, 256, 0, stream>>>(pB, cumB, (float*)d_out);
}

// Round 5
// 6870.591 us; speedup vs baseline: 1.7721x; 1.0116x over previous
//
#include <hip/hip_runtime.h>
#include <hip/hip_bf16.h>
#include <math.h>

#define S_   256
#define B_   32
#define H_   512
#define E_   256
#define V_   10000
#define K_   3
#define T_   32
#define N1_  96
#define BOS_ 1
#define EOS_ 1
#define NEG_ (-1000000000.0f)
#define RT   4        // per-row top-RT kept for exact beam merge (RT > K suffices)
#define LG_MT 79      // ceil(10000/128) m-tiles in logits GEMM
#define GST  (N1_ * 4 * H_)   // gts part stride (floats)

// ---------------------------------------------------------------------------
// Generic fp32 tiled GEMM (prologue + gts): 64x64 tile, TK=16, 256 thr, 4x4
// thread tile, register-prefetch double buffering, split-K via blockIdx.z.
// ---------------------------------------------------------------------------
__global__ __launch_bounds__(256) void gemm_k(
    const float* __restrict__ A, const float* __restrict__ B1,
    const float* __restrict__ B2, int split,
    const float* __restrict__ bias1, const float* __restrict__ bias2,
    float* __restrict__ C, int N, int Kd, int M, int klen, size_t cstride)
{
  __shared__ float As[16][64];
  __shared__ float Bs[16][64];
  const int tid = threadIdx.x;
  const int m0 = blockIdx.x * 64;
  const int n0 = blockIdx.y * 64;
  const int kstart = blockIdx.z * klen;
  const int kend = kstart + klen;
  const int tm = tid & 15, tn = tid >> 4;
  const int la_n = tid & 63;
  const int la_k = (tid >> 6) * 4;
  const int lb_m = (tid & 15) * 4;
  const int lb_k = tid >> 4;

  const int an = (n0 + la_n < N) ? (n0 + la_n) : 0;   // clamp (store guarded)
  const float* Arow = A + (size_t)an * Kd;
  float* Cpart = C + (size_t)blockIdx.z * cstride;

  float4 a_reg, b_reg;
  a_reg = *(const float4*)(Arow + kstart + la_k);
  {
    int krow = kstart + lb_k;
    const float* Brow = (krow < split) ? (B1 + (size_t)krow * M)
                                       : (B2 + (size_t)(krow - split) * M);
    int m = m0 + lb_m;
    if (m + 3 < M) b_reg = *(const float4*)(Brow + m);
    else {
      b_reg.x = (m + 0 < M) ? Brow[m + 0] : 0.f;
      b_reg.y = (m + 1 < M) ? Brow[m + 1] : 0.f;
      b_reg.z = (m + 2 < M) ? Brow[m + 2] : 0.f;
      b_reg.w = (m + 3 < M) ? Brow[m + 3] : 0.f;
    }
  }

  float acc[4][4] = {};

  for (int k0 = kstart; k0 < kend; k0 += 16) {
    if (k0 > kstart) __syncthreads();
    As[la_k + 0][la_n] = a_reg.x; As[la_k + 1][la_n] = a_reg.y;
    As[la_k + 2][la_n] = a_reg.z; As[la_k + 3][la_n] = a_reg.w;
    *(float4*)&Bs[lb_k][lb_m] = b_reg;
    __syncthreads();
    if (k0 + 16 < kend) {
      a_reg = *(const float4*)(Arow + (k0 + 16) + la_k);
      int krow = k0 + 16 + lb_k;
      const float* Brow = (krow < split) ? (B1 + (size_t)krow * M)
                                         : (B2 + (size_t)(krow - split) * M);
      int m = m0 + lb_m;
      if (m + 3 < M) b_reg = *(const float4*)(Brow + m);
      else {
        b_reg.x = (m + 0 < M) ? Brow[m + 0] : 0.f;
        b_reg.y = (m + 1 < M) ? Brow[m + 1] : 0.f;
        b_reg.z = (m + 2 < M) ? Brow[m + 2] : 0.f;
        b_reg.w = (m + 3 < M) ? Brow[m + 3] : 0.f;
      }
    }
#pragma unroll
    for (int kk = 0; kk < 16; kk++) {
      float4 av = *(const float4*)&As[kk][tn * 4];
      float4 bv = *(const float4*)&Bs[kk][tm * 4];
      float a[4] = {av.x, av.y, av.z, av.w};
      float b[4] = {bv.x, bv.y, bv.z, bv.w};
#pragma unroll
      for (int i = 0; i < 4; i++)
#pragma unroll
        for (int j = 0; j < 4; j++) acc[i][j] += a[i] * b[j];
    }
  }

  const bool addBias = (blockIdx.z == 0);
#pragma unroll
  for (int i = 0; i < 4; i++) {
    int n = n0 + tn * 4 + i;
    if (n >= N) continue;
#pragma unroll
    for (int j = 0; j < 4; j++) {
      int m = m0 + tm * 4 + j;
      if (m >= M) continue;
      float v = acc[i][j];
      if (addBias && bias1) v += bias1[m];
      if (addBias && bias2) v += bias2[m];
      Cpart[(size_t)n * M + m] = v;
    }
  }
}

// ---- top-k helpers (jax tie-break: value desc, then smaller index) ----
__device__ __forceinline__ bool tk_better(float va, int ia, float vb, int ib) {
  return (va > vb) || (va == vb && ia < ib);
}
__device__ __forceinline__ void tk_insertN(float v, int i, float* vv, int* ii) {
  if (!tk_better(v, i, vv[RT - 1], ii[RT - 1])) return;
  vv[RT - 1] = v; ii[RT - 1] = i;
#pragma unroll
  for (int q = RT - 1; q > 0; q--) {
    if (tk_better(vv[q], ii[q], vv[q - 1], ii[q - 1])) {
      float tv = vv[q]; vv[q] = vv[q - 1]; vv[q - 1] = tv;
      int ti = ii[q]; ii[q] = ii[q - 1]; ii[q - 1] = ti;
    }
  }
}
// merge sorted list (bv2,bi2) into (av,ai), keep RT best
__device__ __forceinline__ void tk_merge_reg(float* av, int* ai,
                                             const float* bv2, const int* bi2) {
  float rv[RT]; int ri[RT];
  int p = 0, q = 0;
#pragma unroll
  for (int t = 0; t < RT; t++) {
    bool ta;
    if (p >= RT) ta = false;
    else if (q >= RT) ta = true;
    else ta = tk_better(av[p], ai[p], bv2[q], bi2[q]);
    if (ta) { rv[t] = av[p]; ri[t] = ai[p]; p++; }
    else    { rv[t] = bv2[q]; ri[t] = bi2[q]; q++; }
  }
#pragma unroll
  for (int t = 0; t < RT; t++) { av[t] = rv[t]; ai[t] = ri[t]; }
}
// LDS pairwise merge (used by lgmerge_k)
__device__ __forceinline__ void tk_merge_lds(float* sv, int* si, int a, int b) {
  float rv[RT]; int ri[RT];
  int p = 0, q = 0;
#pragma unroll
  for (int t = 0; t < RT; t++) {
    bool ta;
    if (p >= RT) ta = false;
    else if (q >= RT) ta = true;
    else ta = tk_better(sv[a + p], si[a + p], sv[b + q], si[b + q]);
    if (ta) { rv[t] = sv[a + p]; ri[t] = si[a + p]; p++; }
    else    { rv[t] = sv[b + q]; ri[t] = si[b + q]; q++; }
  }
#pragma unroll
  for (int t = 0; t < RT; t++) { sv[a + t] = rv[t]; si[a + t] = ri[t]; }
}

// ---------------------------------------------------------------------------
// Logits GEMM + fused per-tile top-RT / max / expsum epilogue.
// Tile 32 rows x 128 cols, 256 thr, thread tile 4x4 (tm=tid&31 colgrp,
// tn=tid>>5 rowgrp). Grid (LG_MT, ceil(Nrows/32)). lg never materialized.
// ---------------------------------------------------------------------------
__global__ __launch_bounds__(256) void lggemm_k(
    const float* __restrict__ A, const float* __restrict__ Wc,
    const float* __restrict__ bc, int Nrows,
    float* __restrict__ ptv, int* __restrict__ pti,
    float* __restrict__ pmx, float* __restrict__ psm)
{
  __shared__ float As[16][32];
  __shared__ float Bs[16][128];
  const int tid = threadIdx.x;
  const int mt = blockIdx.x;
  const int m0 = mt * 128;
  const int n0 = blockIdx.y * 32;
  const int tm = tid & 31;
  const int tn = tid >> 5;
  // A loader (threads 0..127): row = tid&31, k-quad = ((tid>>5)&3)*4
  const bool aload = tid < 128;
  const int ar = tid & 31;
  const int ak = ((tid >> 5) & 3) * 4;
  const int arow_idx = (n0 + ar < Nrows) ? (n0 + ar) : 0;
  const float* Arow = A + (size_t)arow_idx * 1280;
  // B loader: 2 float4/thread: idx = l*256+tid -> k = idx>>5, c4 = idx&31
  const bool edge = (m0 + 128 > V_);

  float4 a_reg = make_float4(0.f, 0.f, 0.f, 0.f);
  float4 b_reg[2];

  if (aload) a_reg = *(const float4*)(Arow + ak);
#pragma unroll
  for (int l = 0; l < 2; l++) {
    int idx = l * 256 + tid;
    int kr = idx >> 5, c4 = (idx & 31) * 4;
    const float* Brow = Wc + (size_t)kr * V_;
    if (!edge) b_reg[l] = *(const float4*)(Brow + m0 + c4);
    else {
      float4 bv;
      bv.x = (m0 + c4 + 0 < V_) ? Brow[m0 + c4 + 0] : 0.f;
      bv.y = (m0 + c4 + 1 < V_) ? Brow[m0 + c4 + 1] : 0.f;
      bv.z = (m0 + c4 + 2 < V_) ? Brow[m0 + c4 + 2] : 0.f;
      bv.w = (m0 + c4 + 3 < V_) ? Brow[m0 + c4 + 3] : 0.f;
      b_reg[l] = bv;
    }
  }

  float acc[4][4] = {};

  for (int k0 = 0; k0 < 1280; k0 += 16) {
    if (k0 > 0) __syncthreads();
    if (aload) {
      As[ak + 0][ar] = a_reg.x; As[ak + 1][ar] = a_reg.y;
      As[ak + 2][ar] = a_reg.z; As[ak + 3][ar] = a_reg.w;
    }
#pragma unroll
    for (int l = 0; l < 2; l++) {
      int idx = l * 256 + tid;
      int kr = idx >> 5, c4 = (idx & 31) * 4;
      *(float4*)&Bs[kr][c4] = b_reg[l];
    }
    __syncthreads();
    if (k0 + 16 < 1280) {
      if (aload) a_reg = *(const float4*)(Arow + (k0 + 16) + ak);
#pragma unroll
      for (int l = 0; l < 2; l++) {
        int idx = l * 256 + tid;
        int kr = k0 + 16 + (idx >> 5), c4 = (idx & 31) * 4;
        const float* Brow = Wc + (size_t)kr * V_;
        if (!edge) b_reg[l] = *(const float4*)(Brow + m0 + c4);
        else {
          float4 bv;
          bv.x = (m0 + c4 + 0 < V_) ? Brow[m0 + c4 + 0] : 0.f;
          bv.y = (m0 + c4 + 1 < V_) ? Brow[m0 + c4 + 1] : 0.f;
          bv.z = (m0 + c4 + 2 < V_) ? Brow[m0 + c4 + 2] : 0.f;
          bv.w = (m0 + c4 + 3 < V_) ? Brow[m0 + c4 + 3] : 0.f;
          b_reg[l] = bv;
        }
      }
    }
#pragma unroll
    for (int kk = 0; kk < 16; kk++) {
      float4 av = *(const float4*)&As[kk][tn * 4];
      float4 bv = *(const float4*)&Bs[kk][tm * 4];
      float a[4] = {av.x, av.y, av.z, av.w};
      float b[4] = {bv.x, bv.y, bv.z, bv.w};
#pragma unroll
      for (int i = 0; i < 4; i++)
#pragma unroll
        for (int j = 0; j < 4; j++) acc[i][j] += a[i] * b[j];
    }
  }

  // ---- fused epilogue: per-row (of this 128-col tile) top-RT, max, expsum ----
#pragma unroll
  for (int i = 0; i < 4; i++) {
    float vv[RT]; int ii[RT];
#pragma unroll
    for (int q = 0; q < RT; q++) { vv[q] = -3.4e38f; ii[q] = 0x7fffffff; }
    float vals[4];
#pragma unroll
    for (int j = 0; j < 4; j++) {
      int m = m0 + tm * 4 + j;
      float v = (m < V_) ? (acc[i][j] + bc[m]) : -3.4e38f;
      vals[j] = v;
      if (m < V_) tk_insertN(v, m, vv, ii);
    }
    // merge across the 32-lane half-wave (lanes share tn)
#pragma unroll
    for (int off = 1; off < 32; off <<= 1) {
      float ov[RT]; int oi[RT];
#pragma unroll
      for (int q = 0; q < RT; q++) {
        ov[q] = __shfl_xor(vv[q], off);
        oi[q] = __shfl_xor(ii[q], off);
      }
      tk_merge_reg(vv, ii, ov, oi);
    }
    const float rowmax = vv[0];
    float s = 0.f;
#pragma unroll
    for (int j = 0; j < 4; j++) {
      int m = m0 + tm * 4 + j;
      if (m < V_) s += expf(vals[j] - rowmax);
    }
#pragma unroll
    for (int off = 1; off < 32; off <<= 1) s += __shfl_xor(s, off);
    const int gr = n0 + tn * 4 + i;
    if (tm == 0 && gr < Nrows) {
      const size_t pb = (size_t)gr * LG_MT + mt;
#pragma unroll
      for (int q = 0; q < RT; q++) {
        ptv[pb * RT + q] = vv[q]; pti[pb * RT + q] = ii[q];
      }
      pmx[pb] = rowmax;
      psm[pb] = s;
    }
  }
}

// Merge LG_MT per-tile partials per row -> rtv/rti/rmax/rlse. grid Nrows, 128 thr.
__global__ __launch_bounds__(128) void lgmerge_k(
    const float* __restrict__ ptv, const int* __restrict__ pti,
    const float* __restrict__ pmx, const float* __restrict__ psm,
    float* __restrict__ rtv, int* __restrict__ rti,
    float* __restrict__ rmax, float* __restrict__ rlse)
{
  __shared__ float sv[128 * RT];
  __shared__ int si[128 * RT];
  __shared__ float red[128];
  const int n = blockIdx.x, tid = threadIdx.x;
  float mx_t = -3.4e38f, sm_t = 0.f;
  float vv[RT]; int ii[RT];
#pragma unroll
  for (int q = 0; q < RT; q++) { vv[q] = -3.4e38f; ii[q] = 0x7fffffff; }
  if (tid < LG_MT) {
    const size_t pb = (size_t)n * LG_MT + tid;
#pragma unroll
    for (int q = 0; q < RT; q++) { vv[q] = ptv[pb * RT + q]; ii[q] = pti[pb * RT + q]; }
    mx_t = pmx[pb]; sm_t = psm[pb];
  }
#pragma unroll
  for (int q = 0; q < RT; q++) { sv[tid * RT + q] = vv[q]; si[tid * RT + q] = ii[q]; }
  __syncthreads();
  for (int st = 64; st; st >>= 1) {
    if (tid < st) tk_merge_lds(sv, si, tid * RT, (tid + st) * RT);
    __syncthreads();
  }
  red[tid] = mx_t; __syncthreads();
  for (int st = 64; st; st >>= 1) {
    if (tid < st) red[tid] = fmaxf(red[tid], red[tid + st]);
    __syncthreads();
  }
  const float Mg = red[0]; __syncthreads();
  red[tid] = sm_t * expf(mx_t - Mg); __syncthreads();
  for (int st = 64; st; st >>= 1) {
    if (tid < st) red[tid] += red[tid + st];
    __syncthreads();
  }
  if (tid < RT) { rtv[n * RT + tid] = sv[tid]; rti[n * RT + tid] = si[tid]; }
  if (tid == 0) { rmax[n] = Mg; rlse[n] = logf(red[0]); }
}

// ---------------------------------------------------------------------------
// pp[n][m0..m0+63] = sum_k h[n][k] * Wp[k][m].  grid (8, N), 256 thr.
// ---------------------------------------------------------------------------
__global__ __launch_bounds__(256) void ppgemv_k(
    const float* __restrict__ h, const float* __restrict__ Wp,
    float* __restrict__ pp)
{
  __shared__ float hS[512];
  __shared__ float red[256];
  const int n = blockIdx.y, tid = threadIdx.x;
  const int m = blockIdx.x * 64 + (tid & 63);
  const int kg = tid >> 6;
  hS[tid] = h[(size_t)n * H_ + tid];
  hS[256 + tid] = h[(size_t)n * H_ + 256 + tid];
  __syncthreads();
  float acc = 0.f;
#pragma unroll 4
  for (int k = kg * 128; k < kg * 128 + 128; k++)
    acc += hS[k] * Wp[(size_t)k * H_ + m];
  red[tid] = acc;
  __syncthreads();
  if (tid < 64) {
    float v = red[tid] + red[64 + tid] + red[128 + tid] + red[192 + tid];
    pp[(size_t)n * H_ + blockIdx.x * 64 + tid] = v;
  }
}

// ---------------------------------------------------------------------------
// Raw masked scores; stile 0 also fills xcat[ex | .. | hprev].
// grid (8 s-tiles, N), 512 thr.
// ---------------------------------------------------------------------------
__global__ __launch_bounds__(512) void score_k(
    const float* __restrict__ pp, const float* __restrict__ encp,
    const float* __restrict__ Wv, const float* __restrict__ mask,
    const float* __restrict__ emb, const int* __restrict__ tok,
    const float* __restrict__ h, float* __restrict__ sc,
    float* __restrict__ xcat, int bdiv, int tok_is_bos)
{
  __shared__ float ppS[512];
  __shared__ float WvS[512];
  const int n = blockIdx.y, tid = threadIdx.x;
  const int b = n / bdiv;
  ppS[tid] = pp[(size_t)n * H_ + tid];
  WvS[tid] = Wv[tid];
  if (blockIdx.x == 0) {
    xcat[(size_t)n * 1280 + E_ + H_ + tid] = h[(size_t)n * H_ + tid];  // hprev
    if (tid < E_) {
      int tk = tok_is_bos ? BOS_ : tok[n];
      xcat[(size_t)n * 1280 + tid] = emb[(size_t)tk * E_ + tid];       // ex
    }
  }
  __syncthreads();
  const int w = tid >> 6, lane = tid & 63;
#pragma unroll
  for (int j = 0; j < 4; j++) {
    int s = blockIdx.x * 32 + w * 4 + j;
    const float* ep = encp + ((size_t)s * B_ + b) * H_;
    float acc = 0.f;
#pragma unroll
    for (int r = 0; r < 8; r++) {
      int hh = r * 64 + lane;
      acc += tanhf(ppS[hh] + ep[hh]) * WvS[hh];
    }
#pragma unroll
    for (int off = 32; off; off >>= 1) acc += __shfl_xor(acc, off);
    if (lane == 0)
      sc[(size_t)n * S_ + s] = (mask[(size_t)b * S_ + s] == 0.f) ? NEG_ : acc;
  }
}

// ---------------------------------------------------------------------------
// ctx slice with in-block softmax recompute. grid (8 h-tiles, N), 256 thr.
// ---------------------------------------------------------------------------
__global__ __launch_bounds__(256) void ctx_k(
    const float* __restrict__ sc, const float* __restrict__ enc,
    float* __restrict__ xcat, int bdiv)
{
  __shared__ float aS[256];
  __shared__ float red[256];
  const int n = blockIdx.y, tid = threadIdx.x;
  const int b = n / bdiv;
  const int h0 = blockIdx.x * 64;
  float v = sc[(size_t)n * S_ + tid];
  red[tid] = v; __syncthreads();
  for (int st = 128; st; st >>= 1) {
    if (tid < st) red[tid] = fmaxf(red[tid], red[tid + st]);
    __syncthreads();
  }
  const float mx = red[0]; __syncthreads();
  float e = expf(v - mx);
  aS[tid] = e;
  red[tid] = e; __syncthreads();
  for (int st = 128; st; st >>= 1) {
    if (tid < st) red[tid] += red[tid + st];
    __syncthreads();
  }
  const float rsum = 1.f / red[0];
  __syncthreads();
  const int sgrp = tid >> 6, col = tid & 63;
  float acc = 0.f;
#pragma unroll 4
  for (int s0 = 0; s0 < S_; s0 += 4) {
    int s = s0 + sgrp;
    acc += aS[s] * enc[((size_t)s * B_ + b) * H_ + h0 + col];
  }
  red[tid] = acc; __syncthreads();
  if (tid < 64) {
    float total = red[tid] + red[64 + tid] + red[128 + tid] + red[192 + tid];
    xcat[(size_t)n * 1280 + E_ + h0 + tid] = total * rsum;
  }
}

__device__ __forceinline__ float sigf(float x) { return 1.f / (1.f + expf(-x)); }

// LSTM pointwise; sums 4 split-K gts parts; xcat in place: [ex|ctx|hprev]->[ex|h2|ctx].
__global__ __launch_bounds__(256) void lstm_k(
    const float* __restrict__ gts, const float* __restrict__ cprev,
    float* __restrict__ xcat, float* __restrict__ h2, float* __restrict__ c2)
{
  const int n = blockIdx.x, tid = threadIdx.x;
  float* xr = xcat + (size_t)n * 1280;
  for (int i = tid; i < H_; i += 256) {
    float gi = 0.f, gf = 0.f, gg = 0.f, go = 0.f;
#pragma unroll
    for (int p = 0; p < 4; p++) {
      const float* g = gts + (size_t)p * GST + (size_t)n * (4 * H_);
      gi += g[i]; gf += g[H_ + i]; gg += g[2 * H_ + i]; go += g[3 * H_ + i];
    }
    float ctx_i = xr[E_ + i];
    float cc = cprev[(size_t)n * H_ + i];
    float cv = sigf(gf) * cc + sigf(gi) * tanhf(gg);
    float hv = sigf(go) * tanhf(cv);
    c2[(size_t)n * H_ + i] = cv;
    h2[(size_t)n * H_ + i] = hv;
    xr[E_ + i] = hv;
    xr[E_ + H_ + i] = ctx_i;
  }
}

// step-0: beam expand + init. grid 96.
__global__ __launch_bounds__(256) void reorder0_k(
    const float* __restrict__ h2, const float* __restrict__ c2,
    float* __restrict__ h, float* __restrict__ c,
    const float* __restrict__ rtv, const int* __restrict__ rti,
    const float* __restrict__ rmax, const float* __restrict__ rlse,
    float* __restrict__ cum, int* __restrict__ eos, int* __restrict__ tok,
    int* __restrict__ preds)
{
  const int n = blockIdx.x, b = n / K_, r = n % K_, tid = threadIdx.x;
  for (int i = tid; i < H_; i += 256) {
    h[(size_t)n * H_ + i] = h2[(size_t)b * H_ + i];
    c[(size_t)n * H_ + i] = c2[(size_t)b * H_ + i];
  }
  if (tid < T_) preds[tid * N1_ + n] = 0;
  if (tid == 0) {
    float val = (rtv[b * RT + r] - rmax[b]) - rlse[b];
    int idx = rti[b * RT + r];
    preds[n] = idx;
    cum[n] = val; tok[n] = idx; eos[n] = (idx == EOS_) ? 1 : 0;
  }
}

// step-t: 12-candidate exact merge + gather. grid 96.
__global__ __launch_bounds__(256) void reorder1_k(
    const float* __restrict__ h2, const float* __restrict__ c2,
    float* __restrict__ h, float* __restrict__ c,
    const float* __restrict__ rtv, const int* __restrict__ rti,
    const float* __restrict__ rmax, const float* __restrict__ rlse,
    const float* __restrict__ cumOld, float* __restrict__ cumNew,
    const int* __restrict__ eosOld, int* __restrict__ eosNew,
    const int* __restrict__ pOld, int* __restrict__ pNew,
    int* __restrict__ tok, int t)
{
  __shared__ int s_g, s_tok;
  __shared__ float s_val;
  const int n = blockIdx.x, b = n / K_, r = n % K_, tid = threadIdx.x;
  if (tid == 0) {
    float cv[3 * RT]; int cj[3 * RT]; int cnt = 0;
    for (int k = 0; k < K_; k++) {
      int row = b * K_ + k;
      float ck = cumOld[row];
      if (eosOld[row]) {
        cv[cnt] = ck; cj[cnt] = k * V_ + EOS_; cnt++;
      } else {
        float mxk = rmax[row], lsk = rlse[row];
        for (int q = 0; q < RT; q++) {
          cv[cnt] = ck + ((rtv[row * RT + q] - mxk) - lsk);
          cj[cnt] = k * V_ + rti[row * RT + q]; cnt++;
        }
      }
    }
    int used = 0, pick = -1;
    for (int rep = 0; rep <= r; rep++) {
      pick = -1;
      for (int i2 = 0; i2 < cnt; i2++) {
        if ((used >> i2) & 1) continue;
        if (pick < 0 || tk_better(cv[i2], cj[i2], cv[pick], cj[pick])) pick = i2;
      }
      used |= 1 << pick;
    }
    int j = cj[pick];
    s_val = cv[pick];
    s_g = b * K_ + j / V_;
    s_tok = j % V_;
  }
  __syncthreads();
  const int g = s_g, ntok = s_tok;
  for (int i = tid; i < H_; i += 256) {
    h[(size_t)n * H_ + i] = h2[(size_t)g * H_ + i];
    c[(size_t)n * H_ + i] = c2[(size_t)g * H_ + i];
  }
  if (tid < T_) pNew[tid * N1_ + n] = (tid == t) ? ntok : pOld[tid * N1_ + g];
  if (tid == 0) {
    cumNew[n] = s_val;
    eosNew[n] = eosOld[g] | (ntok == EOS_ ? 1 : 0);
    tok[n] = ntok;
  }
}

__global__ __launch_bounds__(256) void finalout_k(
    const int* __restrict__ preds, const float* __restrict__ cum,
    float* __restrict__ out)
{
  const int i = blockIdx.x * 256 + threadIdx.x;
  if (i < T_ * B_) {
    int t = i >> 5, b = i & 31;
    out[i] = (float)preds[t * N1_ + b * K_];
  } else if (i < T_ * B_ + N1_) {
    out[i] = cum[i - T_ * B_];
  }
}

// ---------------------------------------------------------------------------
extern "C" void kernel_launch(void* const* d_in, const int* in_sizes, int n_in,
                              void* d_out, int out_size, void* d_ws, size_t ws_size,
                              hipStream_t stream)
{
  const float* enc    = (const float*)d_in[0];
  const float* last_h = (const float*)d_in[1];
  const float* last_c = (const float*)d_in[2];
  const float* mask   = (const float*)d_in[3];
  const float* emb    = (const float*)d_in[5];
  const float* Wp     = (const float*)d_in[6];
  const float* We     = (const float*)d_in[7];
  const float* Wv     = (const float*)d_in[8];
  const float* W_ih   = (const float*)d_in[9];
  const float* W_hh   = (const float*)d_in[10];
  const float* b_ih   = (const float*)d_in[11];
  const float* b_hh   = (const float*)d_in[12];
  const float* Wc     = (const float*)d_in[13];
  const float* bc     = (const float*)d_in[14];
  const float* W_init = (const float*)d_in[15];
  const float* b_init = (const float*)d_in[16];

  // ws carve — unconditional footprint ~21.8 MB (< proven 23.69 MB)
  float* w = (float*)d_ws;
  float* encp = w;  w += (size_t)S_ * B_ * H_;   // 16.78 MB
  float* h    = w;  w += N1_ * H_;
  float* c    = w;  w += N1_ * H_;
  float* h2   = w;  w += N1_ * H_;
  float* c2   = w;  w += N1_ * H_;
  float* pp   = w;  w += N1_ * H_;
  float* sc   = w;  w += N1_ * S_;
  float* xcat = w;  w += N1_ * 1280;             // doubles as x2 (in-place LSTM)
  float* gts  = w;  w += 4 * GST;                // 4 split-K parts
  float* ptv  = w;  w += (size_t)N1_ * LG_MT * RT;
  float* pmx  = w;  w += (size_t)N1_ * LG_MT;
  float* psm  = w;  w += (size_t)N1_ * LG_MT;
  float* rtv  = w;  w += N1_ * RT;
  float* rmax = w;  w += N1_;
  float* rlse = w;  w += N1_;
  float* cumA = w;  w += N1_;
  float* cumB = w;  w += N1_;
  int* pti  = (int*)w;  w += (size_t)N1_ * LG_MT * RT;
  int* rti  = (int*)w;  w += N1_ * RT;
  int* tok  = (int*)w;  w += N1_;
  int* eosA = (int*)w;  w += N1_;
  int* eosB = (int*)w;  w += N1_;
  int* pA   = (int*)w;  w += T_ * N1_;
  int* pB   = (int*)w;  w += T_ * N1_;

  // ---- prologue ----
  gemm_k<<<dim3(8, 1, 1), 256, 0, stream>>>(last_h + B_ * H_, W_init, nullptr, H_,
      b_init, nullptr, h, B_, H_, H_, H_, 0);
  gemm_k<<<dim3(8, 1, 1), 256, 0, stream>>>(last_c + B_ * H_, W_init, nullptr, H_,
      b_init, nullptr, c, B_, H_, H_, H_, 0);
  gemm_k<<<dim3(8, 128, 1), 256, 0, stream>>>(enc, We, nullptr, H_,
      nullptr, nullptr, encp, S_ * B_, H_, H_, H_, 0);

  for (int t = 0; t < T_; t++) {
    const int N = (t == 0) ? B_ : N1_;
    const int ntiles = (t == 0) ? 1 : 2;         // 64-row tiles for gts gemm
    const int nt32 = (t == 0) ? 1 : 3;           // 32-row tiles for logits gemm
    const int bdiv = (t == 0) ? 1 : K_;

    ppgemv_k<<<dim3(8, N), 256, 0, stream>>>(h, Wp, pp);
    score_k<<<dim3(8, N), 512, 0, stream>>>(pp, encp, Wv, mask, emb, tok, h,
        sc, xcat, bdiv, t == 0 ? 1 : 0);
    ctx_k<<<dim3(8, N), 256, 0, stream>>>(sc, enc, xcat, bdiv);
    gemm_k<<<dim3(32, ntiles, 4), 256, 0, stream>>>(xcat, W_ih, W_hh, E_ + H_,
        b_ih, b_hh, gts, N, 1280, 4 * H_, 320, GST);
    lstm_k<<<N, 256, 0, stream>>>(gts, c, xcat, h2, c2);
    lggemm_k<<<dim3(LG_MT, nt32), 256, 0, stream>>>(xcat, Wc, bc, N,
        ptv, pti, pmx, psm);
    lgmerge_k<<<N, 128, 0, stream>>>(ptv, pti, pmx, psm, rtv, rti, rmax, rlse);
    if (t == 0) {
      reorder0_k<<<N1_, 256, 0, stream>>>(h2, c2, h, c, rtv, rti, rmax, rlse,
          cumA, eosA, tok, pA);
    } else {
      float* cumOld = (t & 1) ? cumA : cumB;
      float* cumNew = (t & 1) ? cumB : cumA;
      int* eosOld = (t & 1) ? eosA : eosB;
      int* eosNew = (t & 1) ? eosB : eosA;
      int* pOld   = (t & 1) ? pA : pB;
      int* pNew   = (t & 1) ? pB : pA;
      reorder1_k<<<N1_, 256, 0, stream>>>(h2, c2, h, c, rtv, rti, rmax, rlse,
          cumOld, cumNew, eosOld, eosNew, pOld, pNew, tok, t);
    }
  }

  // t=31 odd -> preds in pB, cum in cumB
  finalout_k<<<5, 256, 0, stream>>>(pB, cumB, (float*)d_out);
}